// Round 8
// baseline (195.776 us; speedup 1.0000x reference)
//
#include <hip/hip_runtime.h>
#include <hip/hip_fp16.h>

#define D_FEAT 128

typedef _Float16 half8_t __attribute__((ext_vector_type(8)));
typedef float float4_t __attribute__((ext_vector_type(4)));

__device__ __forceinline__ float h16_to_f(unsigned short u) {
    union { unsigned short u; _Float16 f; } cv; cv.u = u; return (float)cv.f;
}
__device__ __forceinline__ unsigned short f_to_h16(float f) {
    union { unsigned short u; _Float16 f; } cv; cv.f = (_Float16)f; return cv.u;
}

// ============================================================================
// Stage 1 (fused): fp32->fp16 convert of input into 4 QUARTER PLANES
// (plane q holds features [q*32, q*32+32) of every node, 64B/node ->
// 3.2MB/plane fits a 4MiB per-XCD L2), + W^T fp16 + edge histogram.
// ============================================================================
__global__ __launch_bounds__(256) void prep_kernel(
    const float* __restrict__ input, unsigned* __restrict__ planes,
    const float* __restrict__ W, __half* __restrict__ wt16,
    const int* __restrict__ erow, int* __restrict__ cnt,
    int nconv4, int n_edges, int n_nodes)
{
    int tid = blockIdx.x * 256 + threadIdx.x;
    if (tid < nconv4) {
        float4 v = reinterpret_cast<const float4*>(input)[tid];
        int node = tid >> 5;          // 32 float4-chunks per node
        int c    = tid & 31;          // chunk covers features c*4..c*4+3
        int q    = c >> 3;            // quarter plane
        __half2 a = __floats2half2_rn(v.x, v.y);
        __half2 b = __floats2half2_rn(v.z, v.w);
        uint2 p;
        p.x = *reinterpret_cast<unsigned*>(&a);
        p.y = *reinterpret_cast<unsigned*>(&b);
        unsigned* dst = planes + ((size_t)q * n_nodes + node) * 16 + (c & 7) * 2;
        *reinterpret_cast<uint2*>(dst) = p;
    } else if (tid < nconv4 + D_FEAT * D_FEAT) {
        int idx = tid - nconv4;
        int n = idx >> 7, k = idx & 127;
        wt16[n * D_FEAT + k] = __float2half(W[k * D_FEAT + n]);
    } else {
        int e = tid - nconv4 - D_FEAT * D_FEAT;
        if (e < n_edges) atomicAdd(&cnt[erow[e]], 1);
    }
}

__global__ __launch_bounds__(256) void hist_kernel(
    const int* __restrict__ erow, int* __restrict__ cnt, int n_edges)
{
    int e = blockIdx.x * 256 + threadIdx.x;
    if (e < n_edges) atomicAdd(&cnt[erow[e]], 1);
}

// fp16 row-major prep (fallback path B)
__global__ __launch_bounds__(256) void prep_noW_kernel(
    const float* __restrict__ input, unsigned* __restrict__ inph_u2,
    const int* __restrict__ erow, int* __restrict__ cnt,
    int nconv4, int n_edges)
{
    int tid = blockIdx.x * 256 + threadIdx.x;
    if (tid < nconv4) {
        float4 v = reinterpret_cast<const float4*>(input)[tid];
        __half2 a = __floats2half2_rn(v.x, v.y);
        __half2 b = __floats2half2_rn(v.z, v.w);
        uint2 p;
        p.x = *reinterpret_cast<unsigned*>(&a);
        p.y = *reinterpret_cast<unsigned*>(&b);
        reinterpret_cast<uint2*>(inph_u2)[tid] = p;
    } else {
        int e = tid - nconv4;
        if (e < n_edges) atomicAdd(&cnt[erow[e]], 1);
    }
}

// ============================================================================
// Stage 2: scan chain (R4-proven structure; chunks double as sort buckets)
// ============================================================================
__global__ __launch_bounds__(256) void partial_kernel(
    const int* __restrict__ cnt, int* __restrict__ partial, int n)
{
    __shared__ int lds[4];
    int i = blockIdx.x * 256 + threadIdx.x;
    int v = (i < n) ? cnt[i] : 0;
#pragma unroll
    for (int off = 32; off > 0; off >>= 1) v += __shfl_down(v, off, 64);
    if ((threadIdx.x & 63) == 0) lds[threadIdx.x >> 6] = v;
    __syncthreads();
    if (threadIdx.x == 0)
        partial[blockIdx.x] = lds[0] + lds[1] + lds[2] + lds[3];
}

__global__ __launch_bounds__(256) void scan_partial_kernel(
    int* __restrict__ partial, int* __restrict__ bcursor,
    int* __restrict__ bbase, int nb, int n_edges)
{
    __shared__ int lds[256];
    int t = threadIdx.x;
    int v = (t < nb) ? partial[t] : 0;
    lds[t] = v;
    __syncthreads();
#pragma unroll
    for (int off = 1; off < 256; off <<= 1) {
        int add = (t >= off) ? lds[t - off] : 0;
        __syncthreads();
        lds[t] += add;
        __syncthreads();
    }
    if (t < nb) {
        int ex = lds[t] - v;
        partial[t] = ex;
        if (bcursor) { bcursor[t] = ex; bbase[t] = ex; }
    }
    if (bcursor && t == 0) bbase[nb] = n_edges;
}

__global__ __launch_bounds__(256) void scan_final_kernel(
    const int* __restrict__ cnt, const int* __restrict__ partial,
    int* __restrict__ cursor, int n)
{
    __shared__ int lds[256];
    int t = threadIdx.x;
    int i = blockIdx.x * 256 + t;
    int v = (i < n) ? cnt[i] : 0;
    lds[t] = v;
    __syncthreads();
#pragma unroll
    for (int off = 1; off < 256; off <<= 1) {
        int add = (t >= off) ? lds[t - off] : 0;
        __syncthreads();
        lds[t] += add;
        __syncthreads();
    }
    if (i < n) cursor[i] = lds[t] - v + partial[blockIdx.x];
}

// ============================================================================
// Stage 3a: bin edges by bucket (= row>>8); LDS hist -> contiguous runs.
// ============================================================================
__global__ __launch_bounds__(256) void bin_kernel(
    const int* __restrict__ erow, const int* __restrict__ ecol,
    const float* __restrict__ ew, int* __restrict__ bcursor,
    uint2* __restrict__ btmp, int n_edges)
{
    __shared__ int lcnt[256];
    const int t = threadIdx.x;
    const int base = blockIdx.x * 4096;
    lcnt[t] = 0;
    __syncthreads();

    unsigned rc[16];
    float    wv[16];
#pragma unroll
    for (int i = 0; i < 16; ++i) {
        int idx = base + i * 256 + t;
        if (idx < n_edges) {
            int r = erow[idx];
            rc[i] = ((unsigned)r << 16) | (unsigned)ecol[idx];
            wv[i] = ew[idx];
            atomicAdd(&lcnt[r >> 8], 1);
        } else {
            rc[i] = 0xFFFFFFFFu;
        }
    }
    __syncthreads();
    int c = lcnt[t];
    int gbase = (c > 0) ? atomicAdd(&bcursor[t], c) : 0;
    lcnt[t] = gbase;
    __syncthreads();
#pragma unroll
    for (int i = 0; i < 16; ++i) {
        if (rc[i] != 0xFFFFFFFFu) {
            int b = rc[i] >> 24;
            int pos = atomicAdd(&lcnt[b], 1);
            uint2 p;
            p.x = rc[i];
            p.y = __float_as_uint(wv[i]);
            btmp[pos] = p;
        }
    }
}

// ============================================================================
// Stage 3b: per-bucket final scatter -> 4B records {w_fp16<<16 | col}.
// ============================================================================
__global__ __launch_bounds__(256) void sort_kernel(
    const uint2* __restrict__ btmp, const int* __restrict__ bbase,
    int* __restrict__ cursor, unsigned* __restrict__ sedge4, int nb)
{
    int b = blockIdx.x;
    int lo = bbase[b];
    int hi = bbase[b + 1];
    for (int i = lo + threadIdx.x; i < hi; i += 256) {
        uint2 p = btmp[i];
        int row = p.x >> 16;
        int pos = atomicAdd(&cursor[row], 1);
        float w = __uint_as_float(p.y);
        sedge4[pos] = (p.x & 0xFFFFu) | ((unsigned)f_to_h16(w) << 16);
    }
}

// ============================================================================
// Stage 4 (path A): quarter-plane SpMM. 4 temporal passes (pass-major block
// order); per pass a wave owns one row: 4 edge-slots x 16 feature-lanes,
// each slot gathers ONE 64B line of the L2-resident 3.2MB plane.
// shfl_xor(16/32) folds the 4 slots. Support written fp16 row-major.
// ============================================================================
__global__ __launch_bounds__(256) void spmm_q_kernel(
    const unsigned* __restrict__ planes, const float* __restrict__ h0,
    const int* __restrict__ cursor, const int* __restrict__ cnt,
    const unsigned* __restrict__ sedge4,
    const float* __restrict__ alpha_p, __half2* __restrict__ s16out, int n)
{
    const int lane = threadIdx.x & 63;
    const int unit = blockIdx.x * 4 + (threadIdx.x >> 6);  // row-pass unit
    const int pass = unit / n;                             // pass-major order
    const int row  = unit - pass * n;
    if (pass >= 4) return;
    const int g  = lane >> 4;     // edge slot 0..3
    const int fl = lane & 15;     // feature lane (2 features)

    const int deg = cnt[row];
    const int beg = cursor[row] - deg;

    const unsigned* plane = planes + (size_t)pass * (size_t)n * 16;

    float2 a0 = {0.f, 0.f}, a1 = {0.f, 0.f};
    int e = 0;
    for (; e + 8 <= deg; e += 8) {
        unsigned r0 = sedge4[beg + e + g];
        unsigned r1 = sedge4[beg + e + 4 + g];
        unsigned v0 = plane[(size_t)(r0 & 0xFFFFu) * 16 + fl];
        unsigned v1 = plane[(size_t)(r1 & 0xFFFFu) * 16 + fl];
        float w0 = h16_to_f((unsigned short)(r0 >> 16));
        float w1 = h16_to_f((unsigned short)(r1 >> 16));
        float2 f0 = __half22float2(*reinterpret_cast<__half2*>(&v0));
        float2 f1 = __half22float2(*reinterpret_cast<__half2*>(&v1));
        a0.x = fmaf(w0, f0.x, a0.x); a0.y = fmaf(w0, f0.y, a0.y);
        a1.x = fmaf(w1, f1.x, a1.x); a1.y = fmaf(w1, f1.y, a1.y);
    }
    for (; e < deg; e += 4) {
        int s = e + g;
        unsigned r0 = (s < deg) ? sedge4[beg + s] : 0u;  // r0=0 -> col0, w=+0
        unsigned v0 = plane[(size_t)(r0 & 0xFFFFu) * 16 + fl];
        float w0 = h16_to_f((unsigned short)(r0 >> 16));
        float2 f0 = __half22float2(*reinterpret_cast<__half2*>(&v0));
        a0.x = fmaf(w0, f0.x, a0.x); a0.y = fmaf(w0, f0.y, a0.y);
    }
    float2 acc;
    acc.x = a0.x + a1.x;
    acc.y = a0.y + a1.y;
    acc.x += __shfl_xor(acc.x, 16, 64);
    acc.y += __shfl_xor(acc.y, 16, 64);
    acc.x += __shfl_xor(acc.x, 32, 64);
    acc.y += __shfl_xor(acc.y, 32, 64);

    if (g == 0) {
        const float alpha = alpha_p[0];
        const float oma   = 1.0f - alpha;
        float2 h = reinterpret_cast<const float2*>(h0)[(size_t)row * 64 + pass * 16 + fl];
        float sx = fmaf(oma, acc.x, alpha * h.x);
        float sy = fmaf(oma, acc.y, alpha * h.y);
        s16out[(size_t)row * 64 + pass * 16 + fl] = __floats2half2_rn(sx, sy);
    }
}

// ============================================================================
// Stage 5 (path A): MFMA GEMM + blend + residual (R6-verified layout).
// ============================================================================
__global__ __launch_bounds__(256) void gemm_mfma_kernel(
    const __half* __restrict__ s16, const __half* __restrict__ wt16,
    const float* __restrict__ input, float* __restrict__ out,
    const float* __restrict__ lamda_p, const int* __restrict__ l_p,
    int n_rows)
{
    const int wave = threadIdx.x >> 6;
    const int lane = threadIdx.x & 63;
    const int row0 = (blockIdx.x * 4 + wave) * 16;
    if (row0 >= n_rows) return;

    const int mr = lane & 15;
    const int kg = lane >> 4;

    const _Float16* sp = reinterpret_cast<const _Float16*>(s16);
    const _Float16* wp = reinterpret_cast<const _Float16*>(wt16);

    float4_t acc[8];
#pragma unroll
    for (int nt = 0; nt < 8; ++nt) acc[nt] = (float4_t){0.f, 0.f, 0.f, 0.f};

#pragma unroll
    for (int ks = 0; ks < 4; ++ks) {
        const int kofs = ks * 32 + kg * 8;
        half8_t a = *reinterpret_cast<const half8_t*>(
            sp + (size_t)(row0 + mr) * D_FEAT + kofs);
#pragma unroll
        for (int nt = 0; nt < 8; ++nt) {
            half8_t b = *reinterpret_cast<const half8_t*>(
                wp + (size_t)(nt * 16 + mr) * D_FEAT + kofs);
            acc[nt] = __builtin_amdgcn_mfma_f32_16x16x32_f16(a, b, acc[nt], 0, 0, 0);
        }
    }

    const float lamda = lamda_p[0];
    const float theta = fminf(1.0f, logf(lamda / (float)l_p[0] + 1.0f));
    const float om_theta = 1.0f - theta;

#pragma unroll
    for (int nt = 0; nt < 8; ++nt) {
#pragma unroll
        for (int r = 0; r < 4; ++r) {
            const int row = row0 + kg * 4 + r;
            const int col = nt * 16 + mr;
            const size_t idx = (size_t)row * D_FEAT + col;
            const float s = (float)sp[idx];
            out[idx] = fmaf(theta, acc[nt][r], fmaf(om_theta, s, input[idx]));
        }
    }
}

// ======================= fallback paths (B/C, from R5) ======================
__global__ __launch_bounds__(256) void edge_scatter_kernel(
    const int* __restrict__ erow, const int* __restrict__ ecol,
    const float* __restrict__ ew, int* __restrict__ cursor,
    uint2* __restrict__ sedge, int n_edges)
{
    int e = blockIdx.x * 256 + threadIdx.x;
    if (e >= n_edges) return;
    int r = erow[e];
    int pos = atomicAdd(&cursor[r], 1);
    uint2 p;
    p.x = (unsigned)ecol[e];
    p.y = __float_as_uint(ew[e]);
    sedge[pos] = p;
}

__global__ __launch_bounds__(256) void spmm_fp16_kernel(
    const __half2* __restrict__ inph, const float* __restrict__ h0,
    const int* __restrict__ cursor, const int* __restrict__ cnt,
    const uint2* __restrict__ sedge,
    const float* __restrict__ alpha_p, float* __restrict__ outp, int n)
{
    int lane = threadIdx.x & 63;
    int row  = blockIdx.x * 4 + (threadIdx.x >> 6);
    if (row >= n) return;
    int deg = cnt[row];
    int beg = cursor[row] - deg;
    float2 accA = make_float2(0.f, 0.f), accB = make_float2(0.f, 0.f);
    int e = 0;
    for (; e + 2 <= deg; e += 2) {
        uint2 e0 = sedge[beg + e], e1 = sedge[beg + e + 1];
        __half2 v0 = inph[(size_t)e0.x * 64 + lane];
        __half2 v1 = inph[(size_t)e1.x * 64 + lane];
        float w0 = __uint_as_float(e0.y), w1 = __uint_as_float(e1.y);
        float2 f0 = __half22float2(v0), f1 = __half22float2(v1);
        accA.x = fmaf(w0, f0.x, accA.x); accA.y = fmaf(w0, f0.y, accA.y);
        accB.x = fmaf(w1, f1.x, accB.x); accB.y = fmaf(w1, f1.y, accB.y);
    }
    if (e < deg) {
        uint2 e0 = sedge[beg + e];
        __half2 v0 = inph[(size_t)e0.x * 64 + lane];
        float w0 = __uint_as_float(e0.y);
        float2 f0 = __half22float2(v0);
        accA.x = fmaf(w0, f0.x, accA.x); accA.y = fmaf(w0, f0.y, accA.y);
    }
    float2 acc; acc.x = accA.x + accB.x; acc.y = accA.y + accB.y;
    const float alpha = alpha_p[0], oma = 1.0f - alpha;
    float2 h = reinterpret_cast<const float2*>(h0)[(size_t)row * 64 + lane];
    float2 s;
    s.x = fmaf(oma, acc.x, alpha * h.x);
    s.y = fmaf(oma, acc.y, alpha * h.y);
    reinterpret_cast<float2*>(outp)[(size_t)row * 64 + lane] = s;
}

__global__ __launch_bounds__(256) void spmm_fp32_kernel(
    const float* __restrict__ input, const float* __restrict__ h0,
    const int* __restrict__ cursor, const int* __restrict__ cnt,
    const uint2* __restrict__ sedge,
    const float* __restrict__ alpha_p, float* __restrict__ outp, int n)
{
    int lane = threadIdx.x & 63;
    int row  = blockIdx.x * 4 + (threadIdx.x >> 6);
    if (row >= n) return;
    int deg = cnt[row];
    int beg = cursor[row] - deg;
    const float2* in2 = reinterpret_cast<const float2*>(input);
    float2 acc = make_float2(0.f, 0.f);
    for (int e = 0; e < deg; ++e) {
        uint2 ed = sedge[beg + e];
        float w = __uint_as_float(ed.y);
        float2 v = in2[(size_t)ed.x * 64 + lane];
        acc.x = fmaf(w, v.x, acc.x);
        acc.y = fmaf(w, v.y, acc.y);
    }
    const float alpha = alpha_p[0], oma = 1.0f - alpha;
    float2 h = reinterpret_cast<const float2*>(h0)[(size_t)row * 64 + lane];
    float2 s;
    s.x = fmaf(oma, acc.x, alpha * h.x);
    s.y = fmaf(oma, acc.y, alpha * h.y);
    reinterpret_cast<float2*>(outp)[(size_t)row * 64 + lane] = s;
}

__global__ __launch_bounds__(256) void fused_kernel(
    float* __restrict__ io, const float* __restrict__ input,
    const float* __restrict__ W,
    const float* __restrict__ lamda_p, const int* __restrict__ l_p,
    int n_rows)
{
    __shared__ float s_lds[2][D_FEAT];
    const int j = threadIdx.x & 127;
    const int r = threadIdx.x >> 7;
    float wcol[D_FEAT];
#pragma unroll
    for (int k = 0; k < D_FEAT; ++k) wcol[k] = W[k * D_FEAT + j];
    const float lamda = lamda_p[0];
    const float theta = fminf(1.0f, logf(lamda / (float)l_p[0] + 1.0f));
    const float om_theta = 1.0f - theta;
    for (int row0 = blockIdx.x * 2; row0 < n_rows; row0 += gridDim.x * 2) {
        const int row = row0 + r;
        const bool active = row < n_rows;
        float sj = 0.0f;
        if (active) {
            sj = io[(size_t)row * D_FEAT + j];
            s_lds[r][j] = sj;
        }
        __syncthreads();
        if (active) {
            float dot = 0.0f;
            const float4* s4 = reinterpret_cast<const float4*>(s_lds[r]);
#pragma unroll
            for (int k4 = 0; k4 < D_FEAT / 4; ++k4) {
                const float4 sv = s4[k4];
                dot = fmaf(sv.x, wcol[4 * k4 + 0], dot);
                dot = fmaf(sv.y, wcol[4 * k4 + 1], dot);
                dot = fmaf(sv.z, wcol[4 * k4 + 2], dot);
                dot = fmaf(sv.w, wcol[4 * k4 + 3], dot);
            }
            const size_t base = (size_t)row * D_FEAT + j;
            io[base] = fmaf(theta, dot, om_theta * sj) + input[base];
        }
        __syncthreads();
    }
}

extern "C" void kernel_launch(void* const* d_in, const int* in_sizes, int n_in,
                              void* d_out, int out_size, void* d_ws, size_t ws_size,
                              hipStream_t stream)
{
    const float* input = (const float*)d_in[0];
    const float* h0    = (const float*)d_in[1];
    const float* W     = (const float*)d_in[2];
    const int*   erow  = (const int*)d_in[3];
    const int*   ecol  = (const int*)d_in[4];
    const float* ew    = (const float*)d_in[5];
    const float* lamda = (const float*)d_in[6];
    const float* alpha = (const float*)d_in[7];
    const int*   l_p   = (const int*)d_in[8];
    float* out = (float*)d_out;

    const int n_nodes = in_sizes[0] / D_FEAT;   // 50000
    const int n_edges = in_sizes[3];            // 800000
    const int nb = (n_nodes + 255) / 256;       // 196
    const int nconv4 = n_nodes * D_FEAT / 4;

    // ---- new-path workspace layout ----
    char* p = (char*)d_ws;
    auto align16 = [](char* q) {
        return (char*)(((uintptr_t)q + 15) & ~(uintptr_t)15);
    };
    int* cnt      = (int*)p;                    p += (size_t)n_nodes * 4;
    int* cursor   = (int*)p;                    p += (size_t)n_nodes * 4;
    int* partial  = (int*)p;                    p += 256 * 4;
    int* bcursor  = (int*)p;                    p += 257 * 4;
    int* bbase    = (int*)p;                    p += 257 * 4;
    p = align16(p);
    unsigned* sedge4 = (unsigned*)p;            p += (size_t)n_edges * 4;
    p = align16(p);
    unsigned* planes = (unsigned*)p;            p += (size_t)n_nodes * D_FEAT * 2;
    p = align16(p);
    char* unionp = p;
    uint2*  btmp = (uint2*)unionp;
    __half* s16  = (__half*)unionp;
    size_t union_bytes = (size_t)n_nodes * D_FEAT * 2;
    if ((size_t)n_edges * 8 > union_bytes) union_bytes = (size_t)n_edges * 8;
    p += union_bytes;
    p = align16(p);
    __half* wt16 = (__half*)p;                  p += (size_t)D_FEAT * D_FEAT * 2;
    const size_t need_new = (size_t)(p - (char*)d_ws);

    const bool use_new = (ws_size >= need_new) && (n_nodes < 65536) && (nb <= 256);

    hipMemsetAsync(cnt, 0, (size_t)n_nodes * sizeof(int), stream);

    if (use_new) {
        int total = nconv4 + D_FEAT * D_FEAT + n_edges;
        prep_kernel<<<(total + 255) / 256, 256, 0, stream>>>(
            input, planes, W, wt16, erow, cnt, nconv4, n_edges, n_nodes);
        partial_kernel<<<nb, 256, 0, stream>>>(cnt, partial, n_nodes);
        scan_partial_kernel<<<1, 256, 0, stream>>>(partial, bcursor, bbase, nb, n_edges);
        scan_final_kernel<<<nb, 256, 0, stream>>>(cnt, partial, cursor, n_nodes);
        bin_kernel<<<(n_edges + 4095) / 4096, 256, 0, stream>>>(
            erow, ecol, ew, bcursor, btmp, n_edges);
        sort_kernel<<<nb, 256, 0, stream>>>(btmp, bbase, cursor, sedge4, nb);
        // 4 passes x n rows, 4 units per block, pass-major ordering
        spmm_q_kernel<<<n_nodes, 256, 0, stream>>>(
            planes, h0, cursor, cnt, sedge4, alpha, (__half2*)s16, n_nodes);
        const int ntiles = (n_nodes + 15) / 16;
        gemm_mfma_kernel<<<(ntiles + 3) / 4, 256, 0, stream>>>(
            s16, wt16, input, out, lamda, l_p, n_nodes);
        return;
    }

    // ---------------- fallback (R5 layout & paths) ----------------
    int*   fcnt     = (int*)d_ws;
    int*   fcursor  = fcnt + n_nodes;
    int*   fpartial = fcursor + n_nodes;
    uint2* fsedge   = (uint2*)(fpartial + 256);
    unsigned* finph = (unsigned*)(fsedge + n_edges);

    const size_t need_base = (size_t)(2 * n_nodes + 256) * 4 + (size_t)n_edges * 8;
    const size_t need_fp16 = need_base + (size_t)n_nodes * D_FEAT * 2;
    const bool use_fp16 = ws_size >= need_fp16;

    if (use_fp16) {
        int total = nconv4 + n_edges;
        prep_noW_kernel<<<(total + 255) / 256, 256, 0, stream>>>(
            input, finph, erow, fcnt, nconv4, n_edges);
    } else {
        hist_kernel<<<(n_edges + 255) / 256, 256, 0, stream>>>(erow, fcnt, n_edges);
    }
    partial_kernel<<<nb, 256, 0, stream>>>(fcnt, fpartial, n_nodes);
    scan_partial_kernel<<<1, 256, 0, stream>>>(fpartial, nullptr, nullptr, nb, n_edges);
    scan_final_kernel<<<nb, 256, 0, stream>>>(fcnt, fpartial, fcursor, n_nodes);
    edge_scatter_kernel<<<(n_edges + 255) / 256, 256, 0, stream>>>(
        erow, ecol, ew, fcursor, fsedge, n_edges);
    if (use_fp16) {
        spmm_fp16_kernel<<<(n_nodes + 3) / 4, 256, 0, stream>>>(
            (const __half2*)finph, h0, fcursor, fcnt, fsedge, alpha, out, n_nodes);
    } else {
        spmm_fp32_kernel<<<(n_nodes + 3) / 4, 256, 0, stream>>>(
            input, h0, fcursor, fcnt, fsedge, alpha, out, n_nodes);
    }
    fused_kernel<<<2048, 256, 0, stream>>>(out, input, W, lamda, l_p, n_nodes);
}

// Round 9
// 172.622 us; speedup vs baseline: 1.1341x; 1.1341x over previous
//
#include <hip/hip_runtime.h>
#include <hip/hip_fp16.h>

#define D_FEAT 128

typedef _Float16 half8_t __attribute__((ext_vector_type(8)));
typedef float float4_t __attribute__((ext_vector_type(4)));

__device__ __forceinline__ float h16_to_f(unsigned short u) {
    union { unsigned short u; _Float16 f; } cv; cv.u = u; return (float)cv.f;
}
__device__ __forceinline__ unsigned short f_to_h16(float f) {
    union { unsigned short u; _Float16 f; } cv; cv.f = (_Float16)f; return cv.u;
}

// ============================================================================
// Stage 1 (fused): fp32->fp16 convert of input (ROW-MAJOR, R7-proven) +
// W^T fp16 + zero 16-slot slack of sedge4 + edge histogram.
// ============================================================================
__global__ __launch_bounds__(256) void prep_kernel(
    const float* __restrict__ input, unsigned* __restrict__ inph_u2,
    const float* __restrict__ W, __half* __restrict__ wt16,
    unsigned* __restrict__ sedge4_slack,
    const int* __restrict__ erow, int* __restrict__ cnt,
    int nconv4, int n_edges)
{
    int tid = blockIdx.x * 256 + threadIdx.x;
    if (tid < nconv4) {
        float4 v = reinterpret_cast<const float4*>(input)[tid];
        __half2 a = __floats2half2_rn(v.x, v.y);
        __half2 b = __floats2half2_rn(v.z, v.w);
        uint2 p;
        p.x = *reinterpret_cast<unsigned*>(&a);
        p.y = *reinterpret_cast<unsigned*>(&b);
        reinterpret_cast<uint2*>(inph_u2)[tid] = p;
    } else if (tid < nconv4 + D_FEAT * D_FEAT) {
        int idx = tid - nconv4;
        int n = idx >> 7, k = idx & 127;
        wt16[n * D_FEAT + k] = __float2half(W[k * D_FEAT + n]);
    } else if (tid < nconv4 + D_FEAT * D_FEAT + 16) {
        sedge4_slack[tid - nconv4 - D_FEAT * D_FEAT] = 0u;
    } else {
        int e = tid - nconv4 - D_FEAT * D_FEAT - 16;
        if (e < n_edges) atomicAdd(&cnt[erow[e]], 1);
    }
}

__global__ __launch_bounds__(256) void hist_kernel(
    const int* __restrict__ erow, int* __restrict__ cnt, int n_edges)
{
    int e = blockIdx.x * 256 + threadIdx.x;
    if (e < n_edges) atomicAdd(&cnt[erow[e]], 1);
}

// fp16 row-major prep (fallback path B)
__global__ __launch_bounds__(256) void prep_noW_kernel(
    const float* __restrict__ input, unsigned* __restrict__ inph_u2,
    const int* __restrict__ erow, int* __restrict__ cnt,
    int nconv4, int n_edges)
{
    int tid = blockIdx.x * 256 + threadIdx.x;
    if (tid < nconv4) {
        float4 v = reinterpret_cast<const float4*>(input)[tid];
        __half2 a = __floats2half2_rn(v.x, v.y);
        __half2 b = __floats2half2_rn(v.z, v.w);
        uint2 p;
        p.x = *reinterpret_cast<unsigned*>(&a);
        p.y = *reinterpret_cast<unsigned*>(&b);
        reinterpret_cast<uint2*>(inph_u2)[tid] = p;
    } else {
        int e = tid - nconv4;
        if (e < n_edges) atomicAdd(&cnt[erow[e]], 1);
    }
}

// ============================================================================
// Stage 2: scan chain (R4-proven structure)
// ============================================================================
__global__ __launch_bounds__(256) void partial_kernel(
    const int* __restrict__ cnt, int* __restrict__ partial, int n)
{
    __shared__ int lds[4];
    int i = blockIdx.x * 256 + threadIdx.x;
    int v = (i < n) ? cnt[i] : 0;
#pragma unroll
    for (int off = 32; off > 0; off >>= 1) v += __shfl_down(v, off, 64);
    if ((threadIdx.x & 63) == 0) lds[threadIdx.x >> 6] = v;
    __syncthreads();
    if (threadIdx.x == 0)
        partial[blockIdx.x] = lds[0] + lds[1] + lds[2] + lds[3];
}

__global__ __launch_bounds__(256) void scan_partial_kernel(
    int* __restrict__ partial, int nb)
{
    __shared__ int lds[256];
    int t = threadIdx.x;
    int v = (t < nb) ? partial[t] : 0;
    lds[t] = v;
    __syncthreads();
#pragma unroll
    for (int off = 1; off < 256; off <<= 1) {
        int add = (t >= off) ? lds[t - off] : 0;
        __syncthreads();
        lds[t] += add;
        __syncthreads();
    }
    if (t < nb) partial[t] = lds[t] - v;
}

__global__ __launch_bounds__(256) void scan_final_kernel(
    const int* __restrict__ cnt, const int* __restrict__ partial,
    int* __restrict__ cursor, int n)
{
    __shared__ int lds[256];
    int t = threadIdx.x;
    int i = blockIdx.x * 256 + t;
    int v = (i < n) ? cnt[i] : 0;
    lds[t] = v;
    __syncthreads();
#pragma unroll
    for (int off = 1; off < 256; off <<= 1) {
        int add = (t >= off) ? lds[t - off] : 0;
        __syncthreads();
        lds[t] += add;
        __syncthreads();
    }
    if (i < n) cursor[i] = lds[t] - v + partial[blockIdx.x];
}

// ============================================================================
// Stage 3: one-pass scatter -> 4B records {w_fp16<<16 | col}.
// Destination array = E*4B = 3.2MB < 4MiB per-XCD L2 -> scattered stores
// accumulate in L2, write back ~once. Edge streams loaded non-temporally
// so they don't evict the scatter window.
// ============================================================================
__global__ __launch_bounds__(256) void scatter4_kernel(
    const int* __restrict__ erow, const int* __restrict__ ecol,
    const float* __restrict__ ew, int* __restrict__ cursor,
    unsigned* __restrict__ sedge4, int n_edges)
{
    int e = blockIdx.x * 256 + threadIdx.x;
    if (e >= n_edges) return;
    int   r = __builtin_nontemporal_load(erow + e);
    int   c = __builtin_nontemporal_load(ecol + e);
    float w = __builtin_nontemporal_load(ew + e);
    int pos = atomicAdd(&cursor[r], 1);
    sedge4[pos] = (unsigned)c | ((unsigned)f_to_h16(w) << 16);
}

// ============================================================================
// Stage 4: CSR SpMM, 4B records, fp16 gather, predicated full-MLP groups of
// 8 (no serial tail: slots >= deg get w=0; record array has zeroed slack).
// Support written fp16 row-major.
// ============================================================================
__global__ __launch_bounds__(256) void spmm4_kernel(
    const __half2* __restrict__ inph, const float* __restrict__ h0,
    const int* __restrict__ cursor, const int* __restrict__ cnt,
    const unsigned* __restrict__ sedge4,
    const float* __restrict__ alpha_p, __half2* __restrict__ s16out, int n)
{
    int lane = threadIdx.x & 63;
    int row  = blockIdx.x * 4 + (threadIdx.x >> 6);
    if (row >= n) return;

    int deg = cnt[row];
    int beg = cursor[row] - deg;

    float2 a0 = {0.f, 0.f}, a1 = {0.f, 0.f}, a2 = {0.f, 0.f}, a3 = {0.f, 0.f};
    for (int e = 0; e < deg; e += 8) {
        // 8 record loads (in-bounds thanks to 16-slot zeroed slack)
        unsigned r0 = sedge4[beg + e + 0];
        unsigned r1 = sedge4[beg + e + 1];
        unsigned r2 = sedge4[beg + e + 2];
        unsigned r3 = sedge4[beg + e + 3];
        unsigned r4 = sedge4[beg + e + 4];
        unsigned r5 = sedge4[beg + e + 5];
        unsigned r6 = sedge4[beg + e + 6];
        unsigned r7 = sedge4[beg + e + 7];
        // 8 independent gathers in flight
        __half2 v0 = inph[(size_t)(r0 & 0xFFFFu) * 64 + lane];
        __half2 v1 = inph[(size_t)(r1 & 0xFFFFu) * 64 + lane];
        __half2 v2 = inph[(size_t)(r2 & 0xFFFFu) * 64 + lane];
        __half2 v3 = inph[(size_t)(r3 & 0xFFFFu) * 64 + lane];
        __half2 v4 = inph[(size_t)(r4 & 0xFFFFu) * 64 + lane];
        __half2 v5 = inph[(size_t)(r5 & 0xFFFFu) * 64 + lane];
        __half2 v6 = inph[(size_t)(r6 & 0xFFFFu) * 64 + lane];
        __half2 v7 = inph[(size_t)(r7 & 0xFFFFu) * 64 + lane];
        // predicated weights: slot >= deg contributes 0
        float w0 = h16_to_f((e + 0 < deg) ? (unsigned short)(r0 >> 16) : (unsigned short)0);
        float w1 = h16_to_f((e + 1 < deg) ? (unsigned short)(r1 >> 16) : (unsigned short)0);
        float w2 = h16_to_f((e + 2 < deg) ? (unsigned short)(r2 >> 16) : (unsigned short)0);
        float w3 = h16_to_f((e + 3 < deg) ? (unsigned short)(r3 >> 16) : (unsigned short)0);
        float w4 = h16_to_f((e + 4 < deg) ? (unsigned short)(r4 >> 16) : (unsigned short)0);
        float w5 = h16_to_f((e + 5 < deg) ? (unsigned short)(r5 >> 16) : (unsigned short)0);
        float w6 = h16_to_f((e + 6 < deg) ? (unsigned short)(r6 >> 16) : (unsigned short)0);
        float w7 = h16_to_f((e + 7 < deg) ? (unsigned short)(r7 >> 16) : (unsigned short)0);
        float2 f;
        f = __half22float2(v0); a0.x = fmaf(w0, f.x, a0.x); a0.y = fmaf(w0, f.y, a0.y);
        f = __half22float2(v1); a1.x = fmaf(w1, f.x, a1.x); a1.y = fmaf(w1, f.y, a1.y);
        f = __half22float2(v2); a2.x = fmaf(w2, f.x, a2.x); a2.y = fmaf(w2, f.y, a2.y);
        f = __half22float2(v3); a3.x = fmaf(w3, f.x, a3.x); a3.y = fmaf(w3, f.y, a3.y);
        f = __half22float2(v4); a0.x = fmaf(w4, f.x, a0.x); a0.y = fmaf(w4, f.y, a0.y);
        f = __half22float2(v5); a1.x = fmaf(w5, f.x, a1.x); a1.y = fmaf(w5, f.y, a1.y);
        f = __half22float2(v6); a2.x = fmaf(w6, f.x, a2.x); a2.y = fmaf(w6, f.y, a2.y);
        f = __half22float2(v7); a3.x = fmaf(w7, f.x, a3.x); a3.y = fmaf(w7, f.y, a3.y);
    }
    float2 acc;
    acc.x = (a0.x + a1.x) + (a2.x + a3.x);
    acc.y = (a0.y + a1.y) + (a2.y + a3.y);

    const float alpha = alpha_p[0];
    const float oma   = 1.0f - alpha;
    float2 h = reinterpret_cast<const float2*>(h0)[(size_t)row * 64 + lane];
    float sx = fmaf(oma, acc.x, alpha * h.x);
    float sy = fmaf(oma, acc.y, alpha * h.y);
    s16out[(size_t)row * 64 + lane] = __floats2half2_rn(sx, sy);
}

// ============================================================================
// Stage 5: MFMA GEMM + blend + residual (R6-verified layout).
// ============================================================================
__global__ __launch_bounds__(256) void gemm_mfma_kernel(
    const __half* __restrict__ s16, const __half* __restrict__ wt16,
    const float* __restrict__ input, float* __restrict__ out,
    const float* __restrict__ lamda_p, const int* __restrict__ l_p,
    int n_rows)
{
    const int wave = threadIdx.x >> 6;
    const int lane = threadIdx.x & 63;
    const int row0 = (blockIdx.x * 4 + wave) * 16;
    if (row0 >= n_rows) return;

    const int mr = lane & 15;
    const int kg = lane >> 4;

    const _Float16* sp = reinterpret_cast<const _Float16*>(s16);
    const _Float16* wp = reinterpret_cast<const _Float16*>(wt16);

    float4_t acc[8];
#pragma unroll
    for (int nt = 0; nt < 8; ++nt) acc[nt] = (float4_t){0.f, 0.f, 0.f, 0.f};

#pragma unroll
    for (int ks = 0; ks < 4; ++ks) {
        const int kofs = ks * 32 + kg * 8;
        half8_t a = *reinterpret_cast<const half8_t*>(
            sp + (size_t)(row0 + mr) * D_FEAT + kofs);
#pragma unroll
        for (int nt = 0; nt < 8; ++nt) {
            half8_t b = *reinterpret_cast<const half8_t*>(
                wp + (size_t)(nt * 16 + mr) * D_FEAT + kofs);
            acc[nt] = __builtin_amdgcn_mfma_f32_16x16x32_f16(a, b, acc[nt], 0, 0, 0);
        }
    }

    const float lamda = lamda_p[0];
    const float theta = fminf(1.0f, logf(lamda / (float)l_p[0] + 1.0f));
    const float om_theta = 1.0f - theta;

#pragma unroll
    for (int nt = 0; nt < 8; ++nt) {
#pragma unroll
        for (int r = 0; r < 4; ++r) {
            const int row = row0 + kg * 4 + r;
            const int col = nt * 16 + mr;
            const size_t idx = (size_t)row * D_FEAT + col;
            const float s = (float)sp[idx];
            out[idx] = fmaf(theta, acc[nt][r], fmaf(om_theta, s, input[idx]));
        }
    }
}

// ======================= fallback paths (B/C, from R5) ======================
__global__ __launch_bounds__(256) void edge_scatter_kernel(
    const int* __restrict__ erow, const int* __restrict__ ecol,
    const float* __restrict__ ew, int* __restrict__ cursor,
    uint2* __restrict__ sedge, int n_edges)
{
    int e = blockIdx.x * 256 + threadIdx.x;
    if (e >= n_edges) return;
    int r = erow[e];
    int pos = atomicAdd(&cursor[r], 1);
    uint2 p;
    p.x = (unsigned)ecol[e];
    p.y = __float_as_uint(ew[e]);
    sedge[pos] = p;
}

__global__ __launch_bounds__(256) void spmm_fp16_kernel(
    const __half2* __restrict__ inph, const float* __restrict__ h0,
    const int* __restrict__ cursor, const int* __restrict__ cnt,
    const uint2* __restrict__ sedge,
    const float* __restrict__ alpha_p, float* __restrict__ outp, int n)
{
    int lane = threadIdx.x & 63;
    int row  = blockIdx.x * 4 + (threadIdx.x >> 6);
    if (row >= n) return;
    int deg = cnt[row];
    int beg = cursor[row] - deg;
    float2 accA = make_float2(0.f, 0.f), accB = make_float2(0.f, 0.f);
    int e = 0;
    for (; e + 2 <= deg; e += 2) {
        uint2 e0 = sedge[beg + e], e1 = sedge[beg + e + 1];
        __half2 v0 = inph[(size_t)e0.x * 64 + lane];
        __half2 v1 = inph[(size_t)e1.x * 64 + lane];
        float w0 = __uint_as_float(e0.y), w1 = __uint_as_float(e1.y);
        float2 f0 = __half22float2(v0), f1 = __half22float2(v1);
        accA.x = fmaf(w0, f0.x, accA.x); accA.y = fmaf(w0, f0.y, accA.y);
        accB.x = fmaf(w1, f1.x, accB.x); accB.y = fmaf(w1, f1.y, accB.y);
    }
    if (e < deg) {
        uint2 e0 = sedge[beg + e];
        __half2 v0 = inph[(size_t)e0.x * 64 + lane];
        float w0 = __uint_as_float(e0.y);
        float2 f0 = __half22float2(v0);
        accA.x = fmaf(w0, f0.x, accA.x); accA.y = fmaf(w0, f0.y, accA.y);
    }
    float2 acc; acc.x = accA.x + accB.x; acc.y = accA.y + accB.y;
    const float alpha = alpha_p[0], oma = 1.0f - alpha;
    float2 h = reinterpret_cast<const float2*>(h0)[(size_t)row * 64 + lane];
    float2 s;
    s.x = fmaf(oma, acc.x, alpha * h.x);
    s.y = fmaf(oma, acc.y, alpha * h.y);
    reinterpret_cast<float2*>(outp)[(size_t)row * 64 + lane] = s;
}

__global__ __launch_bounds__(256) void spmm_fp32_kernel(
    const float* __restrict__ input, const float* __restrict__ h0,
    const int* __restrict__ cursor, const int* __restrict__ cnt,
    const uint2* __restrict__ sedge,
    const float* __restrict__ alpha_p, float* __restrict__ outp, int n)
{
    int lane = threadIdx.x & 63;
    int row  = blockIdx.x * 4 + (threadIdx.x >> 6);
    if (row >= n) return;
    int deg = cnt[row];
    int beg = cursor[row] - deg;
    const float2* in2 = reinterpret_cast<const float2*>(input);
    float2 acc = make_float2(0.f, 0.f);
    for (int e = 0; e < deg; ++e) {
        uint2 ed = sedge[beg + e];
        float w = __uint_as_float(ed.y);
        float2 v = in2[(size_t)ed.x * 64 + lane];
        acc.x = fmaf(w, v.x, acc.x);
        acc.y = fmaf(w, v.y, acc.y);
    }
    const float alpha = alpha_p[0], oma = 1.0f - alpha;
    float2 h = reinterpret_cast<const float2*>(h0)[(size_t)row * 64 + lane];
    float2 s;
    s.x = fmaf(oma, acc.x, alpha * h.x);
    s.y = fmaf(oma, acc.y, alpha * h.y);
    reinterpret_cast<float2*>(outp)[(size_t)row * 64 + lane] = s;
}

__global__ __launch_bounds__(256) void fused_kernel(
    float* __restrict__ io, const float* __restrict__ input,
    const float* __restrict__ W,
    const float* __restrict__ lamda_p, const int* __restrict__ l_p,
    int n_rows)
{
    __shared__ float s_lds[2][D_FEAT];
    const int j = threadIdx.x & 127;
    const int r = threadIdx.x >> 7;
    float wcol[D_FEAT];
#pragma unroll
    for (int k = 0; k < D_FEAT; ++k) wcol[k] = W[k * D_FEAT + j];
    const float lamda = lamda_p[0];
    const float theta = fminf(1.0f, logf(lamda / (float)l_p[0] + 1.0f));
    const float om_theta = 1.0f - theta;
    for (int row0 = blockIdx.x * 2; row0 < n_rows; row0 += gridDim.x * 2) {
        const int row = row0 + r;
        const bool active = row < n_rows;
        float sj = 0.0f;
        if (active) {
            sj = io[(size_t)row * D_FEAT + j];
            s_lds[r][j] = sj;
        }
        __syncthreads();
        if (active) {
            float dot = 0.0f;
            const float4* s4 = reinterpret_cast<const float4*>(s_lds[r]);
#pragma unroll
            for (int k4 = 0; k4 < D_FEAT / 4; ++k4) {
                const float4 sv = s4[k4];
                dot = fmaf(sv.x, wcol[4 * k4 + 0], dot);
                dot = fmaf(sv.y, wcol[4 * k4 + 1], dot);
                dot = fmaf(sv.z, wcol[4 * k4 + 2], dot);
                dot = fmaf(sv.w, wcol[4 * k4 + 3], dot);
            }
            const size_t base = (size_t)row * D_FEAT + j;
            io[base] = fmaf(theta, dot, om_theta * sj) + input[base];
        }
        __syncthreads();
    }
}

extern "C" void kernel_launch(void* const* d_in, const int* in_sizes, int n_in,
                              void* d_out, int out_size, void* d_ws, size_t ws_size,
                              hipStream_t stream)
{
    const float* input = (const float*)d_in[0];
    const float* h0    = (const float*)d_in[1];
    const float* W     = (const float*)d_in[2];
    const int*   erow  = (const int*)d_in[3];
    const int*   ecol  = (const int*)d_in[4];
    const float* ew    = (const float*)d_in[5];
    const float* lamda = (const float*)d_in[6];
    const float* alpha = (const float*)d_in[7];
    const int*   l_p   = (const int*)d_in[8];
    float* out = (float*)d_out;

    const int n_nodes = in_sizes[0] / D_FEAT;   // 50000
    const int n_edges = in_sizes[3];            // 800000
    const int nb = (n_nodes + 255) / 256;       // 196
    const int nconv4 = n_nodes * D_FEAT / 4;

    // ---- new-path workspace layout ----
    // cnt:N | cursor:N | partial:256 | sedge4:(E+16) u32 | inph:N*128 fp16 |
    // s16:N*128 fp16 | wt16:128*128 fp16
    char* p = (char*)d_ws;
    auto align16 = [](char* q) {
        return (char*)(((uintptr_t)q + 15) & ~(uintptr_t)15);
    };
    int* cnt      = (int*)p;                    p += (size_t)n_nodes * 4;
    int* cursor   = (int*)p;                    p += (size_t)n_nodes * 4;
    int* partial  = (int*)p;                    p += 256 * 4;
    p = align16(p);
    unsigned* sedge4 = (unsigned*)p;            p += ((size_t)n_edges + 16) * 4;
    p = align16(p);
    unsigned* inph  = (unsigned*)p;             p += (size_t)n_nodes * D_FEAT * 2;
    p = align16(p);
    __half* s16  = (__half*)p;                  p += (size_t)n_nodes * D_FEAT * 2;
    p = align16(p);
    __half* wt16 = (__half*)p;                  p += (size_t)D_FEAT * D_FEAT * 2;
    const size_t need_new = (size_t)(p - (char*)d_ws);

    const bool use_new = (ws_size >= need_new) && (n_nodes < 65536) && (nb <= 256);

    hipMemsetAsync(cnt, 0, (size_t)n_nodes * sizeof(int), stream);

    if (use_new) {
        int total = nconv4 + D_FEAT * D_FEAT + 16 + n_edges;
        prep_kernel<<<(total + 255) / 256, 256, 0, stream>>>(
            input, inph, W, wt16, sedge4 + n_edges, erow, cnt, nconv4, n_edges);
        partial_kernel<<<nb, 256, 0, stream>>>(cnt, partial, n_nodes);
        scan_partial_kernel<<<1, 256, 0, stream>>>(partial, nb);
        scan_final_kernel<<<nb, 256, 0, stream>>>(cnt, partial, cursor, n_nodes);
        scatter4_kernel<<<(n_edges + 255) / 256, 256, 0, stream>>>(
            erow, ecol, ew, cursor, sedge4, n_edges);
        spmm4_kernel<<<(n_nodes + 3) / 4, 256, 0, stream>>>(
            (const __half2*)inph, h0, cursor, cnt, sedge4, alpha,
            (__half2*)s16, n_nodes);
        const int ntiles = (n_nodes + 15) / 16;
        gemm_mfma_kernel<<<(ntiles + 3) / 4, 256, 0, stream>>>(
            s16, wt16, input, out, lamda, l_p, n_nodes);
        return;
    }

    // ---------------- fallback (R5 layout & paths) ----------------
    int*   fcnt     = (int*)d_ws;
    int*   fcursor  = fcnt + n_nodes;
    int*   fpartial = fcursor + n_nodes;
    uint2* fsedge   = (uint2*)(fpartial + 256);
    unsigned* finph = (unsigned*)(fsedge + n_edges);

    const size_t need_base = (size_t)(2 * n_nodes + 256) * 4 + (size_t)n_edges * 8;
    const size_t need_fp16 = need_base + (size_t)n_nodes * D_FEAT * 2;
    const bool use_fp16 = ws_size >= need_fp16;

    if (use_fp16) {
        int total = nconv4 + n_edges;
        prep_noW_kernel<<<(total + 255) / 256, 256, 0, stream>>>(
            input, finph, erow, fcnt, nconv4, n_edges);
    } else {
        hist_kernel<<<(n_edges + 255) / 256, 256, 0, stream>>>(erow, fcnt, n_edges);
    }
    partial_kernel<<<nb, 256, 0, stream>>>(fcnt, fpartial, n_nodes);
    scan_partial_kernel<<<1, 256, 0, stream>>>(fpartial, nb);
    scan_final_kernel<<<nb, 256, 0, stream>>>(fcnt, fpartial, fcursor, n_nodes);
    edge_scatter_kernel<<<(n_edges + 255) / 256, 256, 0, stream>>>(
        erow, ecol, ew, fcursor, fsedge, n_edges);
    if (use_fp16) {
        spmm_fp16_kernel<<<(n_nodes + 3) / 4, 256, 0, stream>>>(
            (const __half2*)finph, h0, fcursor, fcnt, fsedge, alpha, out, n_nodes);
    } else {
        spmm_fp32_kernel<<<(n_nodes + 3) / 4, 256, 0, stream>>>(
            input, h0, fcursor, fcnt, fsedge, alpha, out, n_nodes);
    }
    fused_kernel<<<2048, 256, 0, stream>>>(out, input, W, lamda, l_p, n_nodes);
}

// Round 10
// 155.256 us; speedup vs baseline: 1.2610x; 1.1119x over previous
//
#include <hip/hip_runtime.h>
#include <hip/hip_fp16.h>

#define D_FEAT 128

typedef _Float16 half8_t __attribute__((ext_vector_type(8)));
typedef float float4_t __attribute__((ext_vector_type(4)));

__device__ __forceinline__ float h16_to_f(unsigned short u) {
    union { unsigned short u; _Float16 f; } cv; cv.u = u; return (float)cv.f;
}
__device__ __forceinline__ unsigned short f_to_h16(float f) {
    union { unsigned short u; _Float16 f; } cv; cv.f = (_Float16)f; return cv.u;
}

// ============================================================================
// Stage 1 (fused): fp32->fp16 convert of input (row-major) + W^T fp16 +
// zero 16-slot slack of sedge4 + per-row edge histogram.
// ============================================================================
__global__ __launch_bounds__(256) void prep_kernel(
    const float* __restrict__ input, unsigned* __restrict__ inph_u2,
    const float* __restrict__ W, __half* __restrict__ wt16,
    unsigned* __restrict__ sedge4_slack,
    const int* __restrict__ erow, int* __restrict__ cnt,
    int nconv4, int n_edges)
{
    int tid = blockIdx.x * 256 + threadIdx.x;
    if (tid < nconv4) {
        float4 v = reinterpret_cast<const float4*>(input)[tid];
        __half2 a = __floats2half2_rn(v.x, v.y);
        __half2 b = __floats2half2_rn(v.z, v.w);
        uint2 p;
        p.x = *reinterpret_cast<unsigned*>(&a);
        p.y = *reinterpret_cast<unsigned*>(&b);
        reinterpret_cast<uint2*>(inph_u2)[tid] = p;
    } else if (tid < nconv4 + D_FEAT * D_FEAT) {
        int idx = tid - nconv4;
        int n = idx >> 7, k = idx & 127;
        wt16[n * D_FEAT + k] = __float2half(W[k * D_FEAT + n]);
    } else if (tid < nconv4 + D_FEAT * D_FEAT + 16) {
        sedge4_slack[tid - nconv4 - D_FEAT * D_FEAT] = 0u;
    } else {
        int e = tid - nconv4 - D_FEAT * D_FEAT - 16;
        if (e < n_edges) atomicAdd(&cnt[erow[e]], 1);
    }
}

__global__ __launch_bounds__(256) void hist_kernel(
    const int* __restrict__ erow, int* __restrict__ cnt, int n_edges)
{
    int e = blockIdx.x * 256 + threadIdx.x;
    if (e < n_edges) atomicAdd(&cnt[erow[e]], 1);
}

// fp16 row-major prep (fallback path B)
__global__ __launch_bounds__(256) void prep_noW_kernel(
    const float* __restrict__ input, unsigned* __restrict__ inph_u2,
    const int* __restrict__ erow, int* __restrict__ cnt,
    int nconv4, int n_edges)
{
    int tid = blockIdx.x * 256 + threadIdx.x;
    if (tid < nconv4) {
        float4 v = reinterpret_cast<const float4*>(input)[tid];
        __half2 a = __floats2half2_rn(v.x, v.y);
        __half2 b = __floats2half2_rn(v.z, v.w);
        uint2 p;
        p.x = *reinterpret_cast<unsigned*>(&a);
        p.y = *reinterpret_cast<unsigned*>(&b);
        reinterpret_cast<uint2*>(inph_u2)[tid] = p;
    } else {
        int e = tid - nconv4;
        if (e < n_edges) atomicAdd(&cnt[erow[e]], 1);
    }
}

// ============================================================================
// Stage 2: scan chain (R4-proven). 256-chunks double as sort BUCKETS;
// scan_partial also emits bcursor (advanced by bin) + bbase (read-only).
// ============================================================================
__global__ __launch_bounds__(256) void partial_kernel(
    const int* __restrict__ cnt, int* __restrict__ partial, int n)
{
    __shared__ int lds[4];
    int i = blockIdx.x * 256 + threadIdx.x;
    int v = (i < n) ? cnt[i] : 0;
#pragma unroll
    for (int off = 32; off > 0; off >>= 1) v += __shfl_down(v, off, 64);
    if ((threadIdx.x & 63) == 0) lds[threadIdx.x >> 6] = v;
    __syncthreads();
    if (threadIdx.x == 0)
        partial[blockIdx.x] = lds[0] + lds[1] + lds[2] + lds[3];
}

__global__ __launch_bounds__(256) void scan_partial_kernel(
    int* __restrict__ partial, int* __restrict__ bcursor,
    int* __restrict__ bbase, int nb, int n_edges)
{
    __shared__ int lds[256];
    int t = threadIdx.x;
    int v = (t < nb) ? partial[t] : 0;
    lds[t] = v;
    __syncthreads();
#pragma unroll
    for (int off = 1; off < 256; off <<= 1) {
        int add = (t >= off) ? lds[t - off] : 0;
        __syncthreads();
        lds[t] += add;
        __syncthreads();
    }
    if (t < nb) {
        int ex = lds[t] - v;
        partial[t] = ex;
        if (bcursor) { bcursor[t] = ex; bbase[t] = ex; }
    }
    if (bcursor && t == 0) bbase[nb] = n_edges;
}

__global__ __launch_bounds__(256) void scan_final_kernel(
    const int* __restrict__ cnt, const int* __restrict__ partial,
    int* __restrict__ cursor, int n)
{
    __shared__ int lds[256];
    int t = threadIdx.x;
    int i = blockIdx.x * 256 + t;
    int v = (i < n) ? cnt[i] : 0;
    lds[t] = v;
    __syncthreads();
#pragma unroll
    for (int off = 1; off < 256; off <<= 1) {
        int add = (t >= off) ? lds[t - off] : 0;
        __syncthreads();
        lds[t] += add;
        __syncthreads();
    }
    if (i < n) cursor[i] = lds[t] - v + partial[blockIdx.x];
}

// ============================================================================
// Stage 3a: bin edges by bucket (= row>>8); LDS hist -> one global atomic
// per (block,bucket) -> contiguous runs per bucket (write-coalesced).
// ============================================================================
__global__ __launch_bounds__(256) void bin_kernel(
    const int* __restrict__ erow, const int* __restrict__ ecol,
    const float* __restrict__ ew, int* __restrict__ bcursor,
    uint2* __restrict__ btmp, int n_edges)
{
    __shared__ int lcnt[256];
    const int t = threadIdx.x;
    const int base = blockIdx.x * 4096;
    lcnt[t] = 0;
    __syncthreads();

    unsigned rc[16];
    float    wv[16];
#pragma unroll
    for (int i = 0; i < 16; ++i) {
        int idx = base + i * 256 + t;
        if (idx < n_edges) {
            int r = erow[idx];
            rc[i] = ((unsigned)r << 16) | (unsigned)ecol[idx];
            wv[i] = ew[idx];
            atomicAdd(&lcnt[r >> 8], 1);
        } else {
            rc[i] = 0xFFFFFFFFu;
        }
    }
    __syncthreads();
    int c = lcnt[t];
    int gbase = (c > 0) ? atomicAdd(&bcursor[t], c) : 0;
    lcnt[t] = gbase;
    __syncthreads();
#pragma unroll
    for (int i = 0; i < 16; ++i) {
        if (rc[i] != 0xFFFFFFFFu) {
            int b = rc[i] >> 24;
            int pos = atomicAdd(&lcnt[b], 1);
            uint2 p;
            p.x = rc[i];
            p.y = __float_as_uint(wv[i]);
            btmp[pos] = p;
        }
    }
}

// ============================================================================
// Stage 3b: per-bucket final scatter -> 4B records {w_fp16<<16 | col}.
// One block per bucket: scatter window ~16KB stays in ONE XCD's L2 ->
// lines fill before write-back (this is what kills the 52MB write-amp).
// ============================================================================
__global__ __launch_bounds__(256) void sort_kernel(
    const uint2* __restrict__ btmp, const int* __restrict__ bbase,
    int* __restrict__ cursor, unsigned* __restrict__ sedge4, int nb)
{
    int b = blockIdx.x;
    int lo = bbase[b];
    int hi = bbase[b + 1];
    for (int i = lo + threadIdx.x; i < hi; i += 256) {
        uint2 p = btmp[i];
        int row = p.x >> 16;
        int pos = atomicAdd(&cursor[row], 1);
        float w = __uint_as_float(p.y);
        sedge4[pos] = (p.x & 0xFFFFu) | ((unsigned)f_to_h16(w) << 16);
    }
}

// ============================================================================
// Stage 4: CSR SpMM, 4B records, fp16 gather. Predicated full-MLP groups of
// 8 (no serial tail: slots >= deg get w=0; record array has zeroed slack).
// ============================================================================
__global__ __launch_bounds__(256) void spmm4_kernel(
    const __half2* __restrict__ inph, const float* __restrict__ h0,
    const int* __restrict__ cursor, const int* __restrict__ cnt,
    const unsigned* __restrict__ sedge4,
    const float* __restrict__ alpha_p, __half2* __restrict__ s16out, int n)
{
    int lane = threadIdx.x & 63;
    int row  = blockIdx.x * 4 + (threadIdx.x >> 6);
    if (row >= n) return;

    int deg = cnt[row];
    int beg = cursor[row] - deg;

    float2 a0 = {0.f, 0.f}, a1 = {0.f, 0.f}, a2 = {0.f, 0.f}, a3 = {0.f, 0.f};
    for (int e = 0; e < deg; e += 8) {
        unsigned r0 = sedge4[beg + e + 0];
        unsigned r1 = sedge4[beg + e + 1];
        unsigned r2 = sedge4[beg + e + 2];
        unsigned r3 = sedge4[beg + e + 3];
        unsigned r4 = sedge4[beg + e + 4];
        unsigned r5 = sedge4[beg + e + 5];
        unsigned r6 = sedge4[beg + e + 6];
        unsigned r7 = sedge4[beg + e + 7];
        __half2 v0 = inph[(size_t)(r0 & 0xFFFFu) * 64 + lane];
        __half2 v1 = inph[(size_t)(r1 & 0xFFFFu) * 64 + lane];
        __half2 v2 = inph[(size_t)(r2 & 0xFFFFu) * 64 + lane];
        __half2 v3 = inph[(size_t)(r3 & 0xFFFFu) * 64 + lane];
        __half2 v4 = inph[(size_t)(r4 & 0xFFFFu) * 64 + lane];
        __half2 v5 = inph[(size_t)(r5 & 0xFFFFu) * 64 + lane];
        __half2 v6 = inph[(size_t)(r6 & 0xFFFFu) * 64 + lane];
        __half2 v7 = inph[(size_t)(r7 & 0xFFFFu) * 64 + lane];
        float w0 = h16_to_f((e + 0 < deg) ? (unsigned short)(r0 >> 16) : (unsigned short)0);
        float w1 = h16_to_f((e + 1 < deg) ? (unsigned short)(r1 >> 16) : (unsigned short)0);
        float w2 = h16_to_f((e + 2 < deg) ? (unsigned short)(r2 >> 16) : (unsigned short)0);
        float w3 = h16_to_f((e + 3 < deg) ? (unsigned short)(r3 >> 16) : (unsigned short)0);
        float w4 = h16_to_f((e + 4 < deg) ? (unsigned short)(r4 >> 16) : (unsigned short)0);
        float w5 = h16_to_f((e + 5 < deg) ? (unsigned short)(r5 >> 16) : (unsigned short)0);
        float w6 = h16_to_f((e + 6 < deg) ? (unsigned short)(r6 >> 16) : (unsigned short)0);
        float w7 = h16_to_f((e + 7 < deg) ? (unsigned short)(r7 >> 16) : (unsigned short)0);
        float2 f;
        f = __half22float2(v0); a0.x = fmaf(w0, f.x, a0.x); a0.y = fmaf(w0, f.y, a0.y);
        f = __half22float2(v1); a1.x = fmaf(w1, f.x, a1.x); a1.y = fmaf(w1, f.y, a1.y);
        f = __half22float2(v2); a2.x = fmaf(w2, f.x, a2.x); a2.y = fmaf(w2, f.y, a2.y);
        f = __half22float2(v3); a3.x = fmaf(w3, f.x, a3.x); a3.y = fmaf(w3, f.y, a3.y);
        f = __half22float2(v4); a0.x = fmaf(w4, f.x, a0.x); a0.y = fmaf(w4, f.y, a0.y);
        f = __half22float2(v5); a1.x = fmaf(w5, f.x, a1.x); a1.y = fmaf(w5, f.y, a1.y);
        f = __half22float2(v6); a2.x = fmaf(w6, f.x, a2.x); a2.y = fmaf(w6, f.y, a2.y);
        f = __half22float2(v7); a3.x = fmaf(w7, f.x, a3.x); a3.y = fmaf(w7, f.y, a3.y);
    }
    float2 acc;
    acc.x = (a0.x + a1.x) + (a2.x + a3.x);
    acc.y = (a0.y + a1.y) + (a2.y + a3.y);

    const float alpha = alpha_p[0];
    const float oma   = 1.0f - alpha;
    float2 h = reinterpret_cast<const float2*>(h0)[(size_t)row * 64 + lane];
    float sx = fmaf(oma, acc.x, alpha * h.x);
    float sy = fmaf(oma, acc.y, alpha * h.y);
    s16out[(size_t)row * 64 + lane] = __floats2half2_rn(sx, sy);
}

// ============================================================================
// Stage 5: MFMA GEMM + blend + residual (R6-verified layout).
// ============================================================================
__global__ __launch_bounds__(256) void gemm_mfma_kernel(
    const __half* __restrict__ s16, const __half* __restrict__ wt16,
    const float* __restrict__ input, float* __restrict__ out,
    const float* __restrict__ lamda_p, const int* __restrict__ l_p,
    int n_rows)
{
    const int wave = threadIdx.x >> 6;
    const int lane = threadIdx.x & 63;
    const int row0 = (blockIdx.x * 4 + wave) * 16;
    if (row0 >= n_rows) return;

    const int mr = lane & 15;
    const int kg = lane >> 4;

    const _Float16* sp = reinterpret_cast<const _Float16*>(s16);
    const _Float16* wp = reinterpret_cast<const _Float16*>(wt16);

    float4_t acc[8];
#pragma unroll
    for (int nt = 0; nt < 8; ++nt) acc[nt] = (float4_t){0.f, 0.f, 0.f, 0.f};

#pragma unroll
    for (int ks = 0; ks < 4; ++ks) {
        const int kofs = ks * 32 + kg * 8;
        half8_t a = *reinterpret_cast<const half8_t*>(
            sp + (size_t)(row0 + mr) * D_FEAT + kofs);
#pragma unroll
        for (int nt = 0; nt < 8; ++nt) {
            half8_t b = *reinterpret_cast<const half8_t*>(
                wp + (size_t)(nt * 16 + mr) * D_FEAT + kofs);
            acc[nt] = __builtin_amdgcn_mfma_f32_16x16x32_f16(a, b, acc[nt], 0, 0, 0);
        }
    }

    const float lamda = lamda_p[0];
    const float theta = fminf(1.0f, logf(lamda / (float)l_p[0] + 1.0f));
    const float om_theta = 1.0f - theta;

#pragma unroll
    for (int nt = 0; nt < 8; ++nt) {
#pragma unroll
        for (int r = 0; r < 4; ++r) {
            const int row = row0 + kg * 4 + r;
            const int col = nt * 16 + mr;
            const size_t idx = (size_t)row * D_FEAT + col;
            const float s = (float)sp[idx];
            out[idx] = fmaf(theta, acc[nt][r], fmaf(om_theta, s, input[idx]));
        }
    }
}

// ======================= fallback paths (B/C, from R5) ======================
__global__ __launch_bounds__(256) void edge_scatter_kernel(
    const int* __restrict__ erow, const int* __restrict__ ecol,
    const float* __restrict__ ew, int* __restrict__ cursor,
    uint2* __restrict__ sedge, int n_edges)
{
    int e = blockIdx.x * 256 + threadIdx.x;
    if (e >= n_edges) return;
    int r = erow[e];
    int pos = atomicAdd(&cursor[r], 1);
    uint2 p;
    p.x = (unsigned)ecol[e];
    p.y = __float_as_uint(ew[e]);
    sedge[pos] = p;
}

__global__ __launch_bounds__(256) void spmm_fp16_kernel(
    const __half2* __restrict__ inph, const float* __restrict__ h0,
    const int* __restrict__ cursor, const int* __restrict__ cnt,
    const uint2* __restrict__ sedge,
    const float* __restrict__ alpha_p, float* __restrict__ outp, int n)
{
    int lane = threadIdx.x & 63;
    int row  = blockIdx.x * 4 + (threadIdx.x >> 6);
    if (row >= n) return;
    int deg = cnt[row];
    int beg = cursor[row] - deg;
    float2 accA = make_float2(0.f, 0.f), accB = make_float2(0.f, 0.f);
    int e = 0;
    for (; e + 2 <= deg; e += 2) {
        uint2 e0 = sedge[beg + e], e1 = sedge[beg + e + 1];
        __half2 v0 = inph[(size_t)e0.x * 64 + lane];
        __half2 v1 = inph[(size_t)e1.x * 64 + lane];
        float w0 = __uint_as_float(e0.y), w1 = __uint_as_float(e1.y);
        float2 f0 = __half22float2(v0), f1 = __half22float2(v1);
        accA.x = fmaf(w0, f0.x, accA.x); accA.y = fmaf(w0, f0.y, accA.y);
        accB.x = fmaf(w1, f1.x, accB.x); accB.y = fmaf(w1, f1.y, accB.y);
    }
    if (e < deg) {
        uint2 e0 = sedge[beg + e];
        __half2 v0 = inph[(size_t)e0.x * 64 + lane];
        float w0 = __uint_as_float(e0.y);
        float2 f0 = __half22float2(v0);
        accA.x = fmaf(w0, f0.x, accA.x); accA.y = fmaf(w0, f0.y, accA.y);
    }
    float2 acc; acc.x = accA.x + accB.x; acc.y = accA.y + accB.y;
    const float alpha = alpha_p[0], oma = 1.0f - alpha;
    float2 h = reinterpret_cast<const float2*>(h0)[(size_t)row * 64 + lane];
    float2 s;
    s.x = fmaf(oma, acc.x, alpha * h.x);
    s.y = fmaf(oma, acc.y, alpha * h.y);
    reinterpret_cast<float2*>(outp)[(size_t)row * 64 + lane] = s;
}

__global__ __launch_bounds__(256) void spmm_fp32_kernel(
    const float* __restrict__ input, const float* __restrict__ h0,
    const int* __restrict__ cursor, const int* __restrict__ cnt,
    const uint2* __restrict__ sedge,
    const float* __restrict__ alpha_p, float* __restrict__ outp, int n)
{
    int lane = threadIdx.x & 63;
    int row  = blockIdx.x * 4 + (threadIdx.x >> 6);
    if (row >= n) return;
    int deg = cnt[row];
    int beg = cursor[row] - deg;
    const float2* in2 = reinterpret_cast<const float2*>(input);
    float2 acc = make_float2(0.f, 0.f);
    for (int e = 0; e < deg; ++e) {
        uint2 ed = sedge[beg + e];
        float w = __uint_as_float(ed.y);
        float2 v = in2[(size_t)ed.x * 64 + lane];
        acc.x = fmaf(w, v.x, acc.x);
        acc.y = fmaf(w, v.y, acc.y);
    }
    const float alpha = alpha_p[0], oma = 1.0f - alpha;
    float2 h = reinterpret_cast<const float2*>(h0)[(size_t)row * 64 + lane];
    float2 s;
    s.x = fmaf(oma, acc.x, alpha * h.x);
    s.y = fmaf(oma, acc.y, alpha * h.y);
    reinterpret_cast<float2*>(outp)[(size_t)row * 64 + lane] = s;
}

__global__ __launch_bounds__(256) void fused_kernel(
    float* __restrict__ io, const float* __restrict__ input,
    const float* __restrict__ W,
    const float* __restrict__ lamda_p, const int* __restrict__ l_p,
    int n_rows)
{
    __shared__ float s_lds[2][D_FEAT];
    const int j = threadIdx.x & 127;
    const int r = threadIdx.x >> 7;
    float wcol[D_FEAT];
#pragma unroll
    for (int k = 0; k < D_FEAT; ++k) wcol[k] = W[k * D_FEAT + j];
    const float lamda = lamda_p[0];
    const float theta = fminf(1.0f, logf(lamda / (float)l_p[0] + 1.0f));
    const float om_theta = 1.0f - theta;
    for (int row0 = blockIdx.x * 2; row0 < n_rows; row0 += gridDim.x * 2) {
        const int row = row0 + r;
        const bool active = row < n_rows;
        float sj = 0.0f;
        if (active) {
            sj = io[(size_t)row * D_FEAT + j];
            s_lds[r][j] = sj;
        }
        __syncthreads();
        if (active) {
            float dot = 0.0f;
            const float4* s4 = reinterpret_cast<const float4*>(s_lds[r]);
#pragma unroll
            for (int k4 = 0; k4 < D_FEAT / 4; ++k4) {
                const float4 sv = s4[k4];
                dot = fmaf(sv.x, wcol[4 * k4 + 0], dot);
                dot = fmaf(sv.y, wcol[4 * k4 + 1], dot);
                dot = fmaf(sv.z, wcol[4 * k4 + 2], dot);
                dot = fmaf(sv.w, wcol[4 * k4 + 3], dot);
            }
            const size_t base = (size_t)row * D_FEAT + j;
            io[base] = fmaf(theta, dot, om_theta * sj) + input[base];
        }
        __syncthreads();
    }
}

extern "C" void kernel_launch(void* const* d_in, const int* in_sizes, int n_in,
                              void* d_out, int out_size, void* d_ws, size_t ws_size,
                              hipStream_t stream)
{
    const float* input = (const float*)d_in[0];
    const float* h0    = (const float*)d_in[1];
    const float* W     = (const float*)d_in[2];
    const int*   erow  = (const int*)d_in[3];
    const int*   ecol  = (const int*)d_in[4];
    const float* ew    = (const float*)d_in[5];
    const float* lamda = (const float*)d_in[6];
    const float* alpha = (const float*)d_in[7];
    const int*   l_p   = (const int*)d_in[8];
    float* out = (float*)d_out;

    const int n_nodes = in_sizes[0] / D_FEAT;   // 50000
    const int n_edges = in_sizes[3];            // 800000
    const int nb = (n_nodes + 255) / 256;       // 196
    const int nconv4 = n_nodes * D_FEAT / 4;

    // ---- new-path workspace layout ----
    // cnt:N | cursor:N | partial:256 | bcursor:257 | bbase:257 |
    // sedge4:(E+16) u32 | inph:N*128 fp16 | union[btmp E uint2 / s16] | wt16
    char* p = (char*)d_ws;
    auto align16 = [](char* q) {
        return (char*)(((uintptr_t)q + 15) & ~(uintptr_t)15);
    };
    int* cnt      = (int*)p;                    p += (size_t)n_nodes * 4;
    int* cursor   = (int*)p;                    p += (size_t)n_nodes * 4;
    int* partial  = (int*)p;                    p += 256 * 4;
    int* bcursor  = (int*)p;                    p += 257 * 4;
    int* bbase    = (int*)p;                    p += 257 * 4;
    p = align16(p);
    unsigned* sedge4 = (unsigned*)p;            p += ((size_t)n_edges + 16) * 4;
    p = align16(p);
    unsigned* inph  = (unsigned*)p;             p += (size_t)n_nodes * D_FEAT * 2;
    p = align16(p);
    char* unionp = p;
    uint2*  btmp = (uint2*)unionp;
    __half* s16  = (__half*)unionp;
    size_t union_bytes = (size_t)n_nodes * D_FEAT * 2;
    if ((size_t)n_edges * 8 > union_bytes) union_bytes = (size_t)n_edges * 8;
    p += union_bytes;
    p = align16(p);
    __half* wt16 = (__half*)p;                  p += (size_t)D_FEAT * D_FEAT * 2;
    const size_t need_new = (size_t)(p - (char*)d_ws);

    const bool use_new = (ws_size >= need_new) && (n_nodes < 65536) && (nb <= 256);

    hipMemsetAsync(cnt, 0, (size_t)n_nodes * sizeof(int), stream);

    if (use_new) {
        int total = nconv4 + D_FEAT * D_FEAT + 16 + n_edges;
        prep_kernel<<<(total + 255) / 256, 256, 0, stream>>>(
            input, inph, W, wt16, sedge4 + n_edges, erow, cnt, nconv4, n_edges);
        partial_kernel<<<nb, 256, 0, stream>>>(cnt, partial, n_nodes);
        scan_partial_kernel<<<1, 256, 0, stream>>>(partial, bcursor, bbase, nb, n_edges);
        scan_final_kernel<<<nb, 256, 0, stream>>>(cnt, partial, cursor, n_nodes);
        bin_kernel<<<(n_edges + 4095) / 4096, 256, 0, stream>>>(
            erow, ecol, ew, bcursor, btmp, n_edges);
        sort_kernel<<<nb, 256, 0, stream>>>(btmp, bbase, cursor, sedge4, nb);
        spmm4_kernel<<<(n_nodes + 3) / 4, 256, 0, stream>>>(
            (const __half2*)inph, h0, cursor, cnt, sedge4, alpha,
            (__half2*)s16, n_nodes);
        const int ntiles = (n_nodes + 15) / 16;
        gemm_mfma_kernel<<<(ntiles + 3) / 4, 256, 0, stream>>>(
            s16, wt16, input, out, lamda, l_p, n_nodes);
        return;
    }

    // ---------------- fallback (R5 layout & paths) ----------------
    int*   fcnt     = (int*)d_ws;
    int*   fcursor  = fcnt + n_nodes;
    int*   fpartial = fcursor + n_nodes;
    uint2* fsedge   = (uint2*)(fpartial + 256);
    unsigned* finph = (unsigned*)(fsedge + n_edges);

    const size_t need_base = (size_t)(2 * n_nodes + 256) * 4 + (size_t)n_edges * 8;
    const size_t need_fp16 = need_base + (size_t)n_nodes * D_FEAT * 2;
    const bool use_fp16 = ws_size >= need_fp16;

    if (use_fp16) {
        int total = nconv4 + n_edges;
        prep_noW_kernel<<<(total + 255) / 256, 256, 0, stream>>>(
            input, finph, erow, fcnt, nconv4, n_edges);
    } else {
        hist_kernel<<<(n_edges + 255) / 256, 256, 0, stream>>>(erow, fcnt, n_edges);
    }
    partial_kernel<<<nb, 256, 0, stream>>>(fcnt, fpartial, n_nodes);
    scan_partial_kernel<<<1, 256, 0, stream>>>(fpartial, nullptr, nullptr, nb, n_edges);
    scan_final_kernel<<<nb, 256, 0, stream>>>(fcnt, fpartial, fcursor, n_nodes);
    edge_scatter_kernel<<<(n_edges + 255) / 256, 256, 0, stream>>>(
        erow, ecol, ew, fcursor, fsedge, n_edges);
    if (use_fp16) {
        spmm_fp16_kernel<<<(n_nodes + 3) / 4, 256, 0, stream>>>(
            (const __half2*)finph, h0, fcursor, fcnt, fsedge, alpha, out, n_nodes);
    } else {
        spmm_fp32_kernel<<<(n_nodes + 3) / 4, 256, 0, stream>>>(
            input, h0, fcursor, fcnt, fsedge, alpha, out, n_nodes);
    }
    fused_kernel<<<2048, 256, 0, stream>>>(out, input, W, lamda, l_p, n_nodes);
}

// Round 11
// 118.131 us; speedup vs baseline: 1.6573x; 1.3143x over previous
//
#include <hip/hip_runtime.h>
#include <hip/hip_fp16.h>

#define D_FEAT 128

typedef _Float16 half8_t __attribute__((ext_vector_type(8)));
typedef float float4_t __attribute__((ext_vector_type(4)));

__device__ __forceinline__ float h16_to_f(unsigned short u) {
    union { unsigned short u; _Float16 f; } cv; cv.u = u; return (float)cv.f;
}
__device__ __forceinline__ unsigned short f_to_h16(float f) {
    union { unsigned short u; _Float16 f; } cv; cv.f = (_Float16)f; return cv.u;
}

// ============================================================================
// Stage 1 (fused, role by blockIdx): input fp32->fp16 | W^T fp16 | zero
// sedge4 slack | BUCKET histogram (LDS-privatized, 256 global atomics per
// 4096-edge block -> no per-row atomic write-through).
// ============================================================================
__global__ __launch_bounds__(256) void prep_kernel(
    const float* __restrict__ input, unsigned* __restrict__ inph_u2,
    const float* __restrict__ W, __half* __restrict__ wt16,
    unsigned* __restrict__ sedge4_slack,
    const int* __restrict__ erow, int* __restrict__ bucket_cnt,
    int nconv4, int n_edges, int convBlocks, int wBlocks)
{
    __shared__ int lh[256];
    const int bid = blockIdx.x;
    const int t = threadIdx.x;

    if (bid < convBlocks) {
        int tid = bid * 256 + t;
        if (tid < nconv4) {
            float4 v = reinterpret_cast<const float4*>(input)[tid];
            __half2 a = __floats2half2_rn(v.x, v.y);
            __half2 b = __floats2half2_rn(v.z, v.w);
            uint2 p;
            p.x = *reinterpret_cast<unsigned*>(&a);
            p.y = *reinterpret_cast<unsigned*>(&b);
            reinterpret_cast<uint2*>(inph_u2)[tid] = p;
        }
    } else if (bid < convBlocks + wBlocks) {
        int idx = (bid - convBlocks) * 256 + t;
        if (idx < D_FEAT * D_FEAT) {
            int n = idx >> 7, k = idx & 127;
            wt16[n * D_FEAT + k] = __float2half(W[k * D_FEAT + n]);
        }
    } else if (bid == convBlocks + wBlocks) {
        if (t < 16) sedge4_slack[t] = 0u;
    } else {
        // bucket histogram: 4096 edges per block
        int hb = bid - convBlocks - wBlocks - 1;
        lh[t] = 0;
        __syncthreads();
        int base = hb * 4096;
        int end = base + 4096; if (end > n_edges) end = n_edges;
        for (int i = base + t; i < end; i += 256)
            atomicAdd(&lh[erow[i] >> 8], 1);
        __syncthreads();
        int c = lh[t];
        if (c > 0) atomicAdd(&bucket_cnt[t], c);
    }
}

// ============================================================================
// Stage 2: exclusive scan of <=256 bucket counts -> bbase (read-only) +
// bcursor (advanced by bin). Single block.
// ============================================================================
__global__ __launch_bounds__(256) void bucket_scan_kernel(
    const int* __restrict__ bucket_cnt, int* __restrict__ bcursor,
    int* __restrict__ bbase, int nb, int n_edges)
{
    __shared__ int lds[256];
    int t = threadIdx.x;
    int v = (t < nb) ? bucket_cnt[t] : 0;
    lds[t] = v;
    __syncthreads();
#pragma unroll
    for (int off = 1; off < 256; off <<= 1) {
        int add = (t >= off) ? lds[t - off] : 0;
        __syncthreads();
        lds[t] += add;
        __syncthreads();
    }
    if (t < nb) {
        int ex = lds[t] - v;
        bcursor[t] = ex;
        bbase[t] = ex;
    }
    if (t == 0) bbase[nb] = n_edges;
}

// ============================================================================
// Stage 3a: bin edges by bucket (= row>>8); LDS hist -> one global atomic
// per (block,bucket) -> contiguous runs per bucket (write-coalesced).
// ============================================================================
__global__ __launch_bounds__(256) void bin_kernel(
    const int* __restrict__ erow, const int* __restrict__ ecol,
    const float* __restrict__ ew, int* __restrict__ bcursor,
    uint2* __restrict__ btmp, int n_edges)
{
    __shared__ int lcnt[256];
    const int t = threadIdx.x;
    const int base = blockIdx.x * 4096;
    lcnt[t] = 0;
    __syncthreads();

    unsigned rc[16];
    float    wv[16];
#pragma unroll
    for (int i = 0; i < 16; ++i) {
        int idx = base + i * 256 + t;
        if (idx < n_edges) {
            int r = erow[idx];
            rc[i] = ((unsigned)r << 16) | (unsigned)ecol[idx];
            wv[i] = ew[idx];
            atomicAdd(&lcnt[r >> 8], 1);
        } else {
            rc[i] = 0xFFFFFFFFu;
        }
    }
    __syncthreads();
    int c = lcnt[t];
    int gbase = (c > 0) ? atomicAdd(&bcursor[t], c) : 0;
    lcnt[t] = gbase;
    __syncthreads();
#pragma unroll
    for (int i = 0; i < 16; ++i) {
        if (rc[i] != 0xFFFFFFFFu) {
            int b = rc[i] >> 24;
            int pos = atomicAdd(&lcnt[b], 1);
            uint2 p;
            p.x = rc[i];
            p.y = __float_as_uint(wv[i]);
            btmp[pos] = p;
        }
    }
}

// ============================================================================
// Stage 3b: per-bucket CSR build + final scatter. One block per bucket:
// LDS histogram of its 256 local rows -> LDS exclusive scan -> writes
// cnt[row] & beg[row] (coalesced!) -> scatters 4B records via LDS cursors.
// Replaces the global row histogram + 3-kernel scan chain entirely.
// ============================================================================
__global__ __launch_bounds__(256) void sort_kernel(
    const uint2* __restrict__ btmp, const int* __restrict__ bbase,
    int* __restrict__ cnt, int* __restrict__ beg,
    unsigned* __restrict__ sedge4, int n)
{
    __shared__ int lscan[256];
    __shared__ int lofs[256];
    const int b = blockIdx.x;
    const int t = threadIdx.x;
    const int lo = bbase[b];
    const int hi = bbase[b + 1];

    lscan[t] = 0;
    __syncthreads();
    for (int i = lo + t; i < hi; i += 256) {
        int rl = (btmp[i].x >> 16) & 255;
        atomicAdd(&lscan[rl], 1);
    }
    __syncthreads();
    int v = lscan[t];
    __syncthreads();
    // exclusive scan over 256 entries (lscan currently holds counts)
#pragma unroll
    for (int off = 1; off < 256; off <<= 1) {
        int add = (t >= off) ? lscan[t - off] : 0;
        __syncthreads();
        lscan[t] += add;
        __syncthreads();
    }
    int ex = lscan[t] - v;
    lofs[t] = ex;
    int row = b * 256 + t;
    if (row < n) {
        cnt[row] = v;
        beg[row] = lo + ex;
    }
    __syncthreads();
    for (int i = lo + t; i < hi; i += 256) {
        uint2 p = btmp[i];
        int rl = (p.x >> 16) & 255;
        int pos = atomicAdd(&lofs[rl], 1);
        float w = __uint_as_float(p.y);
        sedge4[lo + pos] = (p.x & 0xFFFFu) | ((unsigned)f_to_h16(w) << 16);
    }
}

// ============================================================================
// Stage 4: CSR SpMM, 4B records, fp16 gather. Predicated full-MLP groups of
// 8 (no serial tail; record array has zeroed slack).
// ============================================================================
__global__ __launch_bounds__(256) void spmm4_kernel(
    const __half2* __restrict__ inph, const float* __restrict__ h0,
    const int* __restrict__ begp, const int* __restrict__ cnt,
    const unsigned* __restrict__ sedge4,
    const float* __restrict__ alpha_p, __half2* __restrict__ s16out, int n)
{
    int lane = threadIdx.x & 63;
    int row  = blockIdx.x * 4 + (threadIdx.x >> 6);
    if (row >= n) return;

    int deg = cnt[row];
    int beg = begp[row];

    float2 a0 = {0.f, 0.f}, a1 = {0.f, 0.f}, a2 = {0.f, 0.f}, a3 = {0.f, 0.f};
    for (int e = 0; e < deg; e += 8) {
        unsigned r0 = sedge4[beg + e + 0];
        unsigned r1 = sedge4[beg + e + 1];
        unsigned r2 = sedge4[beg + e + 2];
        unsigned r3 = sedge4[beg + e + 3];
        unsigned r4 = sedge4[beg + e + 4];
        unsigned r5 = sedge4[beg + e + 5];
        unsigned r6 = sedge4[beg + e + 6];
        unsigned r7 = sedge4[beg + e + 7];
        __half2 v0 = inph[(size_t)(r0 & 0xFFFFu) * 64 + lane];
        __half2 v1 = inph[(size_t)(r1 & 0xFFFFu) * 64 + lane];
        __half2 v2 = inph[(size_t)(r2 & 0xFFFFu) * 64 + lane];
        __half2 v3 = inph[(size_t)(r3 & 0xFFFFu) * 64 + lane];
        __half2 v4 = inph[(size_t)(r4 & 0xFFFFu) * 64 + lane];
        __half2 v5 = inph[(size_t)(r5 & 0xFFFFu) * 64 + lane];
        __half2 v6 = inph[(size_t)(r6 & 0xFFFFu) * 64 + lane];
        __half2 v7 = inph[(size_t)(r7 & 0xFFFFu) * 64 + lane];
        float w0 = h16_to_f((e + 0 < deg) ? (unsigned short)(r0 >> 16) : (unsigned short)0);
        float w1 = h16_to_f((e + 1 < deg) ? (unsigned short)(r1 >> 16) : (unsigned short)0);
        float w2 = h16_to_f((e + 2 < deg) ? (unsigned short)(r2 >> 16) : (unsigned short)0);
        float w3 = h16_to_f((e + 3 < deg) ? (unsigned short)(r3 >> 16) : (unsigned short)0);
        float w4 = h16_to_f((e + 4 < deg) ? (unsigned short)(r4 >> 16) : (unsigned short)0);
        float w5 = h16_to_f((e + 5 < deg) ? (unsigned short)(r5 >> 16) : (unsigned short)0);
        float w6 = h16_to_f((e + 6 < deg) ? (unsigned short)(r6 >> 16) : (unsigned short)0);
        float w7 = h16_to_f((e + 7 < deg) ? (unsigned short)(r7 >> 16) : (unsigned short)0);
        float2 f;
        f = __half22float2(v0); a0.x = fmaf(w0, f.x, a0.x); a0.y = fmaf(w0, f.y, a0.y);
        f = __half22float2(v1); a1.x = fmaf(w1, f.x, a1.x); a1.y = fmaf(w1, f.y, a1.y);
        f = __half22float2(v2); a2.x = fmaf(w2, f.x, a2.x); a2.y = fmaf(w2, f.y, a2.y);
        f = __half22float2(v3); a3.x = fmaf(w3, f.x, a3.x); a3.y = fmaf(w3, f.y, a3.y);
        f = __half22float2(v4); a0.x = fmaf(w4, f.x, a0.x); a0.y = fmaf(w4, f.y, a0.y);
        f = __half22float2(v5); a1.x = fmaf(w5, f.x, a1.x); a1.y = fmaf(w5, f.y, a1.y);
        f = __half22float2(v6); a2.x = fmaf(w6, f.x, a2.x); a2.y = fmaf(w6, f.y, a2.y);
        f = __half22float2(v7); a3.x = fmaf(w7, f.x, a3.x); a3.y = fmaf(w7, f.y, a3.y);
    }
    float2 acc;
    acc.x = (a0.x + a1.x) + (a2.x + a3.x);
    acc.y = (a0.y + a1.y) + (a2.y + a3.y);

    const float alpha = alpha_p[0];
    const float oma   = 1.0f - alpha;
    float2 h = reinterpret_cast<const float2*>(h0)[(size_t)row * 64 + lane];
    float sx = fmaf(oma, acc.x, alpha * h.x);
    float sy = fmaf(oma, acc.y, alpha * h.y);
    s16out[(size_t)row * 64 + lane] = __floats2half2_rn(sx, sy);
}

// ============================================================================
// Stage 5: MFMA GEMM + blend + residual (R6-verified layout).
// ============================================================================
__global__ __launch_bounds__(256) void gemm_mfma_kernel(
    const __half* __restrict__ s16, const __half* __restrict__ wt16,
    const float* __restrict__ input, float* __restrict__ out,
    const float* __restrict__ lamda_p, const int* __restrict__ l_p,
    int n_rows)
{
    const int wave = threadIdx.x >> 6;
    const int lane = threadIdx.x & 63;
    const int row0 = (blockIdx.x * 4 + wave) * 16;
    if (row0 >= n_rows) return;

    const int mr = lane & 15;
    const int kg = lane >> 4;

    const _Float16* sp = reinterpret_cast<const _Float16*>(s16);
    const _Float16* wp = reinterpret_cast<const _Float16*>(wt16);

    float4_t acc[8];
#pragma unroll
    for (int nt = 0; nt < 8; ++nt) acc[nt] = (float4_t){0.f, 0.f, 0.f, 0.f};

#pragma unroll
    for (int ks = 0; ks < 4; ++ks) {
        const int kofs = ks * 32 + kg * 8;
        half8_t a = *reinterpret_cast<const half8_t*>(
            sp + (size_t)(row0 + mr) * D_FEAT + kofs);
#pragma unroll
        for (int nt = 0; nt < 8; ++nt) {
            half8_t b = *reinterpret_cast<const half8_t*>(
                wp + (size_t)(nt * 16 + mr) * D_FEAT + kofs);
            acc[nt] = __builtin_amdgcn_mfma_f32_16x16x32_f16(a, b, acc[nt], 0, 0, 0);
        }
    }

    const float lamda = lamda_p[0];
    const float theta = fminf(1.0f, logf(lamda / (float)l_p[0] + 1.0f));
    const float om_theta = 1.0f - theta;

#pragma unroll
    for (int nt = 0; nt < 8; ++nt) {
#pragma unroll
        for (int r = 0; r < 4; ++r) {
            const int row = row0 + kg * 4 + r;
            const int col = nt * 16 + mr;
            const size_t idx = (size_t)row * D_FEAT + col;
            const float s = (float)sp[idx];
            out[idx] = fmaf(theta, acc[nt][r], fmaf(om_theta, s, input[idx]));
        }
    }
}

// ======================= fallback paths (B/C, from R5) ======================
__global__ __launch_bounds__(256) void hist_kernel(
    const int* __restrict__ erow, int* __restrict__ cnt, int n_edges)
{
    int e = blockIdx.x * 256 + threadIdx.x;
    if (e < n_edges) atomicAdd(&cnt[erow[e]], 1);
}

__global__ __launch_bounds__(256) void prep_noW_kernel(
    const float* __restrict__ input, unsigned* __restrict__ inph_u2,
    const int* __restrict__ erow, int* __restrict__ cnt,
    int nconv4, int n_edges)
{
    int tid = blockIdx.x * 256 + threadIdx.x;
    if (tid < nconv4) {
        float4 v = reinterpret_cast<const float4*>(input)[tid];
        __half2 a = __floats2half2_rn(v.x, v.y);
        __half2 b = __floats2half2_rn(v.z, v.w);
        uint2 p;
        p.x = *reinterpret_cast<unsigned*>(&a);
        p.y = *reinterpret_cast<unsigned*>(&b);
        reinterpret_cast<uint2*>(inph_u2)[tid] = p;
    } else {
        int e = tid - nconv4;
        if (e < n_edges) atomicAdd(&cnt[erow[e]], 1);
    }
}

__global__ __launch_bounds__(256) void partial_kernel(
    const int* __restrict__ cnt, int* __restrict__ partial, int n)
{
    __shared__ int lds[4];
    int i = blockIdx.x * 256 + threadIdx.x;
    int v = (i < n) ? cnt[i] : 0;
#pragma unroll
    for (int off = 32; off > 0; off >>= 1) v += __shfl_down(v, off, 64);
    if ((threadIdx.x & 63) == 0) lds[threadIdx.x >> 6] = v;
    __syncthreads();
    if (threadIdx.x == 0)
        partial[blockIdx.x] = lds[0] + lds[1] + lds[2] + lds[3];
}

__global__ __launch_bounds__(256) void scan_partial_kernel(
    int* __restrict__ partial, int nb)
{
    __shared__ int lds[256];
    int t = threadIdx.x;
    int v = (t < nb) ? partial[t] : 0;
    lds[t] = v;
    __syncthreads();
#pragma unroll
    for (int off = 1; off < 256; off <<= 1) {
        int add = (t >= off) ? lds[t - off] : 0;
        __syncthreads();
        lds[t] += add;
        __syncthreads();
    }
    if (t < nb) partial[t] = lds[t] - v;
}

__global__ __launch_bounds__(256) void scan_final_kernel(
    const int* __restrict__ cnt, const int* __restrict__ partial,
    int* __restrict__ cursor, int n)
{
    __shared__ int lds[256];
    int t = threadIdx.x;
    int i = blockIdx.x * 256 + t;
    int v = (i < n) ? cnt[i] : 0;
    lds[t] = v;
    __syncthreads();
#pragma unroll
    for (int off = 1; off < 256; off <<= 1) {
        int add = (t >= off) ? lds[t - off] : 0;
        __syncthreads();
        lds[t] += add;
        __syncthreads();
    }
    if (i < n) cursor[i] = lds[t] - v + partial[blockIdx.x];
}

__global__ __launch_bounds__(256) void edge_scatter_kernel(
    const int* __restrict__ erow, const int* __restrict__ ecol,
    const float* __restrict__ ew, int* __restrict__ cursor,
    uint2* __restrict__ sedge, int n_edges)
{
    int e = blockIdx.x * 256 + threadIdx.x;
    if (e >= n_edges) return;
    int r = erow[e];
    int pos = atomicAdd(&cursor[r], 1);
    uint2 p;
    p.x = (unsigned)ecol[e];
    p.y = __float_as_uint(ew[e]);
    sedge[pos] = p;
}

__global__ __launch_bounds__(256) void spmm_fp16_kernel(
    const __half2* __restrict__ inph, const float* __restrict__ h0,
    const int* __restrict__ cursor, const int* __restrict__ cnt,
    const uint2* __restrict__ sedge,
    const float* __restrict__ alpha_p, float* __restrict__ outp, int n)
{
    int lane = threadIdx.x & 63;
    int row  = blockIdx.x * 4 + (threadIdx.x >> 6);
    if (row >= n) return;
    int deg = cnt[row];
    int beg = cursor[row] - deg;
    float2 accA = make_float2(0.f, 0.f), accB = make_float2(0.f, 0.f);
    int e = 0;
    for (; e + 2 <= deg; e += 2) {
        uint2 e0 = sedge[beg + e], e1 = sedge[beg + e + 1];
        __half2 v0 = inph[(size_t)e0.x * 64 + lane];
        __half2 v1 = inph[(size_t)e1.x * 64 + lane];
        float w0 = __uint_as_float(e0.y), w1 = __uint_as_float(e1.y);
        float2 f0 = __half22float2(v0), f1 = __half22float2(v1);
        accA.x = fmaf(w0, f0.x, accA.x); accA.y = fmaf(w0, f0.y, accA.y);
        accB.x = fmaf(w1, f1.x, accB.x); accB.y = fmaf(w1, f1.y, accB.y);
    }
    if (e < deg) {
        uint2 e0 = sedge[beg + e];
        __half2 v0 = inph[(size_t)e0.x * 64 + lane];
        float w0 = __uint_as_float(e0.y);
        float2 f0 = __half22float2(v0);
        accA.x = fmaf(w0, f0.x, accA.x); accA.y = fmaf(w0, f0.y, accA.y);
    }
    float2 acc; acc.x = accA.x + accB.x; acc.y = accA.y + accB.y;
    const float alpha = alpha_p[0], oma = 1.0f - alpha;
    float2 h = reinterpret_cast<const float2*>(h0)[(size_t)row * 64 + lane];
    float2 s;
    s.x = fmaf(oma, acc.x, alpha * h.x);
    s.y = fmaf(oma, acc.y, alpha * h.y);
    reinterpret_cast<float2*>(outp)[(size_t)row * 64 + lane] = s;
}

__global__ __launch_bounds__(256) void spmm_fp32_kernel(
    const float* __restrict__ input, const float* __restrict__ h0,
    const int* __restrict__ cursor, const int* __restrict__ cnt,
    const uint2* __restrict__ sedge,
    const float* __restrict__ alpha_p, float* __restrict__ outp, int n)
{
    int lane = threadIdx.x & 63;
    int row  = blockIdx.x * 4 + (threadIdx.x >> 6);
    if (row >= n) return;
    int deg = cnt[row];
    int beg = cursor[row] - deg;
    const float2* in2 = reinterpret_cast<const float2*>(input);
    float2 acc = make_float2(0.f, 0.f);
    for (int e = 0; e < deg; ++e) {
        uint2 ed = sedge[beg + e];
        float w = __uint_as_float(ed.y);
        float2 v = in2[(size_t)ed.x * 64 + lane];
        acc.x = fmaf(w, v.x, acc.x);
        acc.y = fmaf(w, v.y, acc.y);
    }
    const float alpha = alpha_p[0], oma = 1.0f - alpha;
    float2 h = reinterpret_cast<const float2*>(h0)[(size_t)row * 64 + lane];
    float2 s;
    s.x = fmaf(oma, acc.x, alpha * h.x);
    s.y = fmaf(oma, acc.y, alpha * h.y);
    reinterpret_cast<float2*>(outp)[(size_t)row * 64 + lane] = s;
}

__global__ __launch_bounds__(256) void fused_kernel(
    float* __restrict__ io, const float* __restrict__ input,
    const float* __restrict__ W,
    const float* __restrict__ lamda_p, const int* __restrict__ l_p,
    int n_rows)
{
    __shared__ float s_lds[2][D_FEAT];
    const int j = threadIdx.x & 127;
    const int r = threadIdx.x >> 7;
    float wcol[D_FEAT];
#pragma unroll
    for (int k = 0; k < D_FEAT; ++k) wcol[k] = W[k * D_FEAT + j];
    const float lamda = lamda_p[0];
    const float theta = fminf(1.0f, logf(lamda / (float)l_p[0] + 1.0f));
    const float om_theta = 1.0f - theta;
    for (int row0 = blockIdx.x * 2; row0 < n_rows; row0 += gridDim.x * 2) {
        const int row = row0 + r;
        const bool active = row < n_rows;
        float sj = 0.0f;
        if (active) {
            sj = io[(size_t)row * D_FEAT + j];
            s_lds[r][j] = sj;
        }
        __syncthreads();
        if (active) {
            float dot = 0.0f;
            const float4* s4 = reinterpret_cast<const float4*>(s_lds[r]);
#pragma unroll
            for (int k4 = 0; k4 < D_FEAT / 4; ++k4) {
                const float4 sv = s4[k4];
                dot = fmaf(sv.x, wcol[4 * k4 + 0], dot);
                dot = fmaf(sv.y, wcol[4 * k4 + 1], dot);
                dot = fmaf(sv.z, wcol[4 * k4 + 2], dot);
                dot = fmaf(sv.w, wcol[4 * k4 + 3], dot);
            }
            const size_t base = (size_t)row * D_FEAT + j;
            io[base] = fmaf(theta, dot, om_theta * sj) + input[base];
        }
        __syncthreads();
    }
}

extern "C" void kernel_launch(void* const* d_in, const int* in_sizes, int n_in,
                              void* d_out, int out_size, void* d_ws, size_t ws_size,
                              hipStream_t stream)
{
    const float* input = (const float*)d_in[0];
    const float* h0    = (const float*)d_in[1];
    const float* W     = (const float*)d_in[2];
    const int*   erow  = (const int*)d_in[3];
    const int*   ecol  = (const int*)d_in[4];
    const float* ew    = (const float*)d_in[5];
    const float* lamda = (const float*)d_in[6];
    const float* alpha = (const float*)d_in[7];
    const int*   l_p   = (const int*)d_in[8];
    float* out = (float*)d_out;

    const int n_nodes = in_sizes[0] / D_FEAT;   // 50000
    const int n_edges = in_sizes[3];            // 800000
    const int nb = (n_nodes + 255) / 256;       // 196
    const int nconv4 = n_nodes * D_FEAT / 4;

    // ---- new-path workspace layout ----
    // cnt:N | beg:N | bucket_cnt:256 | bcursor:257 | bbase:257 |
    // sedge4:(E+16) u32 | inph:N*128 fp16 | union[btmp E uint2 / s16] | wt16
    char* p = (char*)d_ws;
    auto align16 = [](char* q) {
        return (char*)(((uintptr_t)q + 15) & ~(uintptr_t)15);
    };
    int* cnt      = (int*)p;                    p += (size_t)n_nodes * 4;
    int* beg      = (int*)p;                    p += (size_t)n_nodes * 4;
    int* bucket_cnt = (int*)p;                  p += 256 * 4;
    int* bcursor  = (int*)p;                    p += 257 * 4;
    int* bbase    = (int*)p;                    p += 257 * 4;
    p = align16(p);
    unsigned* sedge4 = (unsigned*)p;            p += ((size_t)n_edges + 16) * 4;
    p = align16(p);
    unsigned* inph  = (unsigned*)p;             p += (size_t)n_nodes * D_FEAT * 2;
    p = align16(p);
    char* unionp = p;
    uint2*  btmp = (uint2*)unionp;
    __half* s16  = (__half*)unionp;
    size_t union_bytes = (size_t)n_nodes * D_FEAT * 2;
    if ((size_t)n_edges * 8 > union_bytes) union_bytes = (size_t)n_edges * 8;
    p += union_bytes;
    p = align16(p);
    __half* wt16 = (__half*)p;                  p += (size_t)D_FEAT * D_FEAT * 2;
    const size_t need_new = (size_t)(p - (char*)d_ws);

    const bool use_new = (ws_size >= need_new) && (n_nodes < 65536) && (nb <= 256);

    if (use_new) {
        const int convBlocks = (nconv4 + 255) / 256;
        const int wBlocks = (D_FEAT * D_FEAT + 255) / 256;
        const int histBlocks = (n_edges + 4095) / 4096;
        const int totalBlocks = convBlocks + wBlocks + 1 + histBlocks;

        hipMemsetAsync(bucket_cnt, 0, 256 * sizeof(int), stream);
        prep_kernel<<<totalBlocks, 256, 0, stream>>>(
            input, inph, W, wt16, sedge4 + n_edges, erow, bucket_cnt,
            nconv4, n_edges, convBlocks, wBlocks);
        bucket_scan_kernel<<<1, 256, 0, stream>>>(
            bucket_cnt, bcursor, bbase, nb, n_edges);
        bin_kernel<<<histBlocks, 256, 0, stream>>>(
            erow, ecol, ew, bcursor, btmp, n_edges);
        sort_kernel<<<nb, 256, 0, stream>>>(
            btmp, bbase, cnt, beg, sedge4, n_nodes);
        spmm4_kernel<<<(n_nodes + 3) / 4, 256, 0, stream>>>(
            (const __half2*)inph, h0, beg, cnt, sedge4, alpha,
            (__half2*)s16, n_nodes);
        const int ntiles = (n_nodes + 15) / 16;
        gemm_mfma_kernel<<<(ntiles + 3) / 4, 256, 0, stream>>>(
            s16, wt16, input, out, lamda, l_p, n_nodes);
        return;
    }

    // ---------------- fallback (R5 layout & paths) ----------------
    int*   fcnt     = (int*)d_ws;
    int*   fcursor  = fcnt + n_nodes;
    int*   fpartial = fcursor + n_nodes;
    uint2* fsedge   = (uint2*)(fpartial + 256);
    unsigned* finph = (unsigned*)(fsedge + n_edges);

    const size_t need_base = (size_t)(2 * n_nodes + 256) * 4 + (size_t)n_edges * 8;
    const size_t need_fp16 = need_base + (size_t)n_nodes * D_FEAT * 2;
    const bool use_fp16 = ws_size >= need_fp16;

    hipMemsetAsync(fcnt, 0, (size_t)n_nodes * sizeof(int), stream);

    if (use_fp16) {
        int total = nconv4 + n_edges;
        prep_noW_kernel<<<(total + 255) / 256, 256, 0, stream>>>(
            input, finph, erow, fcnt, nconv4, n_edges);
    } else {
        hist_kernel<<<(n_edges + 255) / 256, 256, 0, stream>>>(erow, fcnt, n_edges);
    }
    partial_kernel<<<nb, 256, 0, stream>>>(fcnt, fpartial, n_nodes);
    scan_partial_kernel<<<1, 256, 0, stream>>>(fpartial, nb);
    scan_final_kernel<<<nb, 256, 0, stream>>>(fcnt, fpartial, fcursor, n_nodes);
    edge_scatter_kernel<<<(n_edges + 255) / 256, 256, 0, stream>>>(
        erow, ecol, ew, fcursor, fsedge, n_edges);
    if (use_fp16) {
        spmm_fp16_kernel<<<(n_nodes + 3) / 4, 256, 0, stream>>>(
            (const __half2*)finph, h0, fcursor, fcnt, fsedge, alpha, out, n_nodes);
    } else {
        spmm_fp32_kernel<<<(n_nodes + 3) / 4, 256, 0, stream>>>(
            input, h0, fcursor, fcnt, fsedge, alpha, out, n_nodes);
    }
    fused_kernel<<<2048, 256, 0, stream>>>(out, input, W, lamda, l_p, n_nodes);
}